// Round 1
// baseline (3797.918 us; speedup 1.0000x reference)
//
#include <hip/hip_runtime.h>
#include <cstdint>
#include <cstdio>

#define T_LEN 2048
#define D_DIM 1024
#define HQn 16
#define HKVn 4
#define HDn 64
#define NE 8
#define FF 2752
#define NTOK 2048
#define NSLOT 4096
#define ATT_SCALE 0.125f

// ---------------- RMSNorm: one block per row, D=1024, 256 thr x float4 ----------------
__global__ __launch_bounds__(256) void k_rmsnorm(const float* __restrict__ x,
                                                 const float* __restrict__ g,
                                                 float* __restrict__ out) {
  int row = blockIdx.x;
  int t = threadIdx.x;
  const float4* x4 = (const float4*)(x + (size_t)row * D_DIM);
  float4 v = x4[t];
  float ss = v.x * v.x + v.y * v.y + v.z * v.z + v.w * v.w;
#pragma unroll
  for (int off = 32; off; off >>= 1) ss += __shfl_xor(ss, off, 64);
  __shared__ float red[4];
  if ((t & 63) == 0) red[t >> 6] = ss;
  __syncthreads();
  float tot = red[0] + red[1] + red[2] + red[3];
  float sc = rsqrtf(tot * (1.0f / D_DIM) + 1e-6f);
  const float4* g4 = (const float4*)g;
  float4 gv = g4[t];
  float4 o;
  o.x = v.x * gv.x * sc;
  o.y = v.y * gv.y * sc;
  o.z = v.z * gv.z * sc;
  o.w = v.w * gv.w * sc;
  ((float4*)(out + (size_t)row * D_DIM))[t] = o;
}

// ---------------- generic fp32 GEMM: C[M,N] = A[M,K]@B[K,N] (+res) ----------------
// tiles 64x64x16, 256 threads, 4x4 per thread. M,N,K multiples of tile sizes.
__global__ __launch_bounds__(256) void k_gemm(const float* __restrict__ A,
                                              const float* __restrict__ B,
                                              float* __restrict__ C,
                                              const float* __restrict__ res,
                                              int M, int N, int K) {
  __shared__ float As[16][65];
  __shared__ float Bs[16][65];
  int tid = threadIdx.x;
  int tx = tid & 15, ty = tid >> 4;
  int m0 = blockIdx.y * 64, n0 = blockIdx.x * 64;
  float acc[4][4] = {};
  for (int k0 = 0; k0 < K; k0 += 16) {
#pragma unroll
    for (int i = 0; i < 4; i++) {
      int li = tid + i * 256;
      int m = li >> 4, kk = li & 15;
      As[kk][m] = A[(size_t)(m0 + m) * K + k0 + kk];
    }
#pragma unroll
    for (int i = 0; i < 4; i++) {
      int li = tid + i * 256;
      int n = li & 63, kk = li >> 6;
      Bs[kk][n] = B[(size_t)(k0 + kk) * N + n0 + n];
    }
    __syncthreads();
#pragma unroll
    for (int kk = 0; kk < 16; kk++) {
      float a[4], b[4];
#pragma unroll
      for (int i = 0; i < 4; i++) a[i] = As[kk][ty * 4 + i];
#pragma unroll
      for (int j = 0; j < 4; j++) b[j] = Bs[kk][tx * 4 + j];
#pragma unroll
      for (int i = 0; i < 4; i++)
#pragma unroll
        for (int j = 0; j < 4; j++) acc[i][j] += a[i] * b[j];
    }
    __syncthreads();
  }
#pragma unroll
  for (int i = 0; i < 4; i++) {
    int m = m0 + ty * 4 + i;
#pragma unroll
    for (int j = 0; j < 4; j++) {
      int n = n0 + tx * 4 + j;
      float vv = acc[i][j];
      if (res) vv += res[(size_t)m * N + n];
      C[(size_t)m * N + n] = vv;
    }
  }
}

// ---------------- RoPE in-place on q [T, 1024] and k [T, 256] ----------------
__global__ __launch_bounds__(256) void k_rope(float* __restrict__ q, float* __restrict__ k) {
  int t = blockIdx.x;
  for (int it = threadIdx.x; it < (HQn + HKVn) * 32; it += 256) {
    int hh = it >> 5;
    int i = it & 31;
    float freq = powf(10000.0f, -(float)i / 32.0f);
    float ang = (float)t * freq;
    float c = cosf(ang), sn = sinf(ang);
    float* p = (hh < HQn) ? (q + (size_t)t * (HQn * HDn) + hh * HDn)
                          : (k + (size_t)t * (HKVn * HDn) + (hh - HQn) * HDn);
    float a = p[i], b = p[i + 32];
    p[i] = a * c - b * sn;
    p[i + 32] = b * c + a * sn;
  }
}

// ---------------- flash attention: 1 wave per q-row, 4 rows/block ----------------
__global__ __launch_bounds__(256) void k_attn(const float* __restrict__ q,
                                              const float* __restrict__ kbuf,
                                              const float* __restrict__ vbuf,
                                              float* __restrict__ o) {
  int qh = blockIdx.y;
  int kvh = qh >> 2;  // G = 4
  int r0 = blockIdx.x * 4;
  int tid = threadIdx.x;
  int wave = tid >> 6, lane = tid & 63;
  int row = r0 + wave;

  __shared__ float Ks[64][68];  // padded, row stride 272B (16B aligned)
  __shared__ float Vs[64][64];
  __shared__ float Qs[4][64];

  Qs[tid >> 6][tid & 63] = q[(size_t)(r0 + (tid >> 6)) * (HQn * HDn) + qh * HDn + (tid & 63)];

  float m = -INFINITY, l = 0.f, oacc = 0.f;
  int cmax = (r0 + 3) >> 6;
  for (int c = 0; c <= cmax; c++) {
#pragma unroll
    for (int i = 0; i < 16; i++) {
      int li = tid + i * 256;
      int j = li >> 6, d = li & 63;
      size_t src = (size_t)(c * 64 + j) * (HKVn * HDn) + kvh * HDn + d;
      Ks[j][d] = kbuf[src];
      Vs[j][d] = vbuf[src];
    }
    __syncthreads();
    int jk = c * 64 + lane;
    const float4* qv = (const float4*)(&Qs[wave][0]);
    const float4* kv = (const float4*)(&Ks[lane][0]);
    float s = 0.f;
#pragma unroll
    for (int i = 0; i < 16; i++) {
      float4 a = qv[i], b = kv[i];
      s += a.x * b.x + a.y * b.y + a.z * b.z + a.w * b.w;
    }
    s *= ATT_SCALE;
    if (jk > row) s = -1e30f;
    float cm = s;
#pragma unroll
    for (int off = 32; off; off >>= 1) cm = fmaxf(cm, __shfl_xor(cm, off, 64));
    float mn = fmaxf(m, cm);
    float p = expf(s - mn);
    float alpha = expf(m - mn);
    float ps = p;
#pragma unroll
    for (int off = 32; off; off >>= 1) ps += __shfl_xor(ps, off, 64);
    l = l * alpha + ps;
    oacc *= alpha;
    for (int j = 0; j < 64; j++) {
      float pj = __shfl(p, j, 64);
      oacc += pj * Vs[j][lane];
    }
    m = mn;
    __syncthreads();
  }
  o[(size_t)row * (HQn * HDn) + qh * HDn + lane] = oacc / l;
}

// ---------------- gate: 1 wave per token ----------------
__global__ __launch_bounds__(256) void k_gate(const float* __restrict__ h,
                                              const float* __restrict__ gw,
                                              int* __restrict__ counts,
                                              int* __restrict__ ids,
                                              float* __restrict__ wts,
                                              float* __restrict__ load_sum) {
  int wave = threadIdx.x >> 6, lane = threadIdx.x & 63;
  int token = blockIdx.x * 4 + wave;
  const float* hp = h + (size_t)token * D_DIM;
  float acc[NE] = {};
  for (int d = lane; d < D_DIM; d += 64) {
    float hv = hp[d];
#pragma unroll
    for (int e = 0; e < NE; e++) acc[e] += hv * gw[d * NE + e];
  }
#pragma unroll
  for (int e = 0; e < NE; e++)
#pragma unroll
    for (int off = 32; off; off >>= 1) acc[e] += __shfl_xor(acc[e], off, 64);
  if (lane == 0) {
    float mx = acc[0];
#pragma unroll
    for (int e = 1; e < NE; e++) mx = fmaxf(mx, acc[e]);
    float p[NE], sum = 0.f;
#pragma unroll
    for (int e = 0; e < NE; e++) { p[e] = expf(acc[e] - mx); sum += p[e]; }
#pragma unroll
    for (int e = 0; e < NE; e++) p[e] /= sum;
    int i1 = 0;
#pragma unroll
    for (int e = 1; e < NE; e++) if (p[e] > p[i1]) i1 = e;
    int i2 = (i1 == 0) ? 1 : 0;
#pragma unroll
    for (int e = 0; e < NE; e++) if (e != i1 && p[e] > p[i2]) i2 = e;
    float denom = p[i1] + p[i2] + 1e-8f;
    float w1 = p[i1] / denom, w2 = p[i2] / denom;
    int pos = atomicAdd(&counts[i1], 1);
    ids[i1 * NTOK + pos] = token;
    wts[i1 * NTOK + pos] = w1;
    pos = atomicAdd(&counts[i2], 1);
    ids[i2 * NTOK + pos] = token;
    wts[i2 * NTOK + pos] = w2;
#pragma unroll
    for (int e = 0; e < NE; e++) atomicAdd(&load_sum[e], p[e]);
  }
}

__global__ void k_offsets(const int* __restrict__ counts, int* __restrict__ offsets) {
  if (threadIdx.x == 0 && blockIdx.x == 0) {
    int s = 0;
    for (int e = 0; e < NE; e++) { offsets[e] = s; s += counts[e]; }
  }
}

// ---------------- expert gate/up GEMM + SiLU*up*w -> act ----------------
__global__ __launch_bounds__(256) void k_moe_gateup(const float* __restrict__ h,
                                                    const float* __restrict__ we_gate,
                                                    const float* __restrict__ we_up,
                                                    const int* __restrict__ ids,
                                                    const float* __restrict__ wts,
                                                    const int* __restrict__ counts,
                                                    const int* __restrict__ offsets,
                                                    float* __restrict__ act) {
  int e = blockIdx.z;
  int cnt = counts[e];
  int m0 = blockIdx.y * 64;
  if (m0 >= cnt) return;
  int n0 = blockIdx.x * 64;
  __shared__ float As[16][65];
  __shared__ float Bg[16][65];
  __shared__ float Bu[16][65];
  __shared__ int toks[64];
  __shared__ float wrow[64];
  int tid = threadIdx.x;
  if (tid < 64) {
    int mm = m0 + tid;
    toks[tid] = (mm < cnt) ? ids[e * NTOK + mm] : 0;
    wrow[tid] = (mm < cnt) ? wts[e * NTOK + mm] : 0.f;
  }
  __syncthreads();
  int tx = tid & 15, ty = tid >> 4;
  float accg[4][4] = {}, accu[4][4] = {};
  const float* Bgp = we_gate + (size_t)e * D_DIM * FF;
  const float* Bup = we_up + (size_t)e * D_DIM * FF;
  for (int k0 = 0; k0 < D_DIM; k0 += 16) {
#pragma unroll
    for (int i = 0; i < 4; i++) {
      int li = tid + i * 256;
      int mm = li >> 4, kk = li & 15;
      As[kk][mm] = h[(size_t)toks[mm] * D_DIM + k0 + kk];
    }
#pragma unroll
    for (int i = 0; i < 4; i++) {
      int li = tid + i * 256;
      int n = li & 63, kk = li >> 6;
      Bg[kk][n] = Bgp[(size_t)(k0 + kk) * FF + n0 + n];
      Bu[kk][n] = Bup[(size_t)(k0 + kk) * FF + n0 + n];
    }
    __syncthreads();
#pragma unroll
    for (int kk = 0; kk < 16; kk++) {
      float a[4], bg[4], bu[4];
#pragma unroll
      for (int i = 0; i < 4; i++) a[i] = As[kk][ty * 4 + i];
#pragma unroll
      for (int j = 0; j < 4; j++) { bg[j] = Bg[kk][tx * 4 + j]; bu[j] = Bu[kk][tx * 4 + j]; }
#pragma unroll
      for (int i = 0; i < 4; i++)
#pragma unroll
        for (int j = 0; j < 4; j++) { accg[i][j] += a[i] * bg[j]; accu[i][j] += a[i] * bu[j]; }
    }
    __syncthreads();
  }
  int slot0 = offsets[e] + m0;
#pragma unroll
  for (int i = 0; i < 4; i++) {
    int ml = ty * 4 + i;
    if (m0 + ml < cnt) {
      float w = wrow[ml];
#pragma unroll
      for (int j = 0; j < 4; j++) {
        float gv = accg[i][j];
        float uv = accu[i][j];
        float silu = gv / (1.0f + expf(-gv));
        act[(size_t)(slot0 + ml) * FF + n0 + tx * 4 + j] = silu * uv * w;
      }
    }
  }
}

// ---------------- expert down GEMM, scatter-add into moe_acc ----------------
__global__ __launch_bounds__(256) void k_moe_down(const float* __restrict__ act,
                                                  const float* __restrict__ we_down,
                                                  const int* __restrict__ ids,
                                                  const int* __restrict__ counts,
                                                  const int* __restrict__ offsets,
                                                  float* __restrict__ moe_acc) {
  int e = blockIdx.z;
  int cnt = counts[e];
  int m0 = blockIdx.y * 64;
  if (m0 >= cnt) return;
  int n0 = blockIdx.x * 64;
  __shared__ float As[16][65];
  __shared__ float Bs[16][65];
  __shared__ int toks[64];
  int tid = threadIdx.x;
  if (tid < 64) {
    int mm = m0 + tid;
    toks[tid] = (mm < cnt) ? ids[e * NTOK + mm] : 0;
  }
  __syncthreads();
  int tx = tid & 15, ty = tid >> 4;
  float acc[4][4] = {};
  int arow0 = offsets[e] + m0;
  const float* Bp = we_down + (size_t)e * FF * D_DIM;
  for (int k0 = 0; k0 < FF; k0 += 16) {
#pragma unroll
    for (int i = 0; i < 4; i++) {
      int li = tid + i * 256;
      int mm = li >> 4, kk = li & 15;
      As[kk][mm] = act[(size_t)(arow0 + mm) * FF + k0 + kk];
    }
#pragma unroll
    for (int i = 0; i < 4; i++) {
      int li = tid + i * 256;
      int n = li & 63, kk = li >> 6;
      Bs[kk][n] = Bp[(size_t)(k0 + kk) * D_DIM + n0 + n];
    }
    __syncthreads();
#pragma unroll
    for (int kk = 0; kk < 16; kk++) {
      float a[4], b[4];
#pragma unroll
      for (int i = 0; i < 4; i++) a[i] = As[kk][ty * 4 + i];
#pragma unroll
      for (int j = 0; j < 4; j++) b[j] = Bs[kk][tx * 4 + j];
#pragma unroll
      for (int i = 0; i < 4; i++)
#pragma unroll
        for (int j = 0; j < 4; j++) acc[i][j] += a[i] * b[j];
    }
    __syncthreads();
  }
#pragma unroll
  for (int i = 0; i < 4; i++) {
    int ml = ty * 4 + i;
    if (m0 + ml < cnt) {
      int token = toks[ml];
#pragma unroll
      for (int j = 0; j < 4; j++)
        atomicAdd(&moe_acc[(size_t)token * D_DIM + n0 + tx * 4 + j], acc[i][j]);
    }
  }
}

// ---------------- final: out = x1 + moe_acc ----------------
__global__ __launch_bounds__(256) void k_add(const float* __restrict__ a,
                                             const float* __restrict__ b,
                                             float* __restrict__ o) {
  int i = blockIdx.x * 256 + threadIdx.x;
  float4 va = ((const float4*)a)[i];
  float4 vb = ((const float4*)b)[i];
  float4 vo;
  vo.x = va.x + vb.x; vo.y = va.y + vb.y; vo.z = va.z + vb.z; vo.w = va.w + vb.w;
  ((float4*)o)[i] = vo;
}

__global__ void k_aux(const int* __restrict__ counts, const float* __restrict__ load_sum,
                      float* __restrict__ out_aux) {
  if (threadIdx.x == 0 && blockIdx.x == 0) {
    float s = 0.f;
    for (int e = 0; e < NE; e++)
      s += ((float)counts[e] / (float)NSLOT) * (load_sum[e] / (float)NTOK);
    *out_aux = 0.01f * (float)NE * s;
  }
}

extern "C" void kernel_launch(void* const* d_in, const int* in_sizes, int n_in,
                              void* d_out, int out_size, void* d_ws, size_t ws_size,
                              hipStream_t stream) {
  const float* x = (const float*)d_in[0];
  const float* g1 = (const float*)d_in[1];
  const float* g2 = (const float*)d_in[2];
  const float* wq = (const float*)d_in[3];
  const float* wk = (const float*)d_in[4];
  const float* wv = (const float*)d_in[5];
  const float* wo = (const float*)d_in[6];
  const float* gate_w = (const float*)d_in[7];
  const float* we_gate = (const float*)d_in[8];
  const float* we_up = (const float*)d_in[9];
  const float* we_down = (const float*)d_in[10];
  float* out = (float*)d_out;

  float* ws = (float*)d_ws;
  size_t off = 0;
  float* h = ws + off;        off += (size_t)NTOK * D_DIM;           // 2M
  float* qb = ws + off;       off += (size_t)NTOK * HQn * HDn;       // 2M
  float* kb = ws + off;       off += (size_t)NTOK * HKVn * HDn;      // 0.5M
  float* vb = ws + off;       off += (size_t)NTOK * HKVn * HDn;      // 0.5M
  float* ob = ws + off;       off += (size_t)NTOK * D_DIM;           // 2M
  float* x1 = ws + off;       off += (size_t)NTOK * D_DIM;           // 2M
  float* moe_acc = ws + off;  off += (size_t)NTOK * D_DIM;           // 2M
  float* act = ws + off;      off += (size_t)(NSLOT + 64) * FF;      // ~11.4M
  int* counts = (int*)(ws + off);   off += NE;
  int* offsets = (int*)(ws + off);  off += NE;
  float* load_sum = ws + off;       off += NE;
  int* ids = (int*)(ws + off);      off += NE * NTOK;
  float* wts = ws + off;            off += NE * NTOK;
  // total ~23.0M floats (~92 MB)

  hipMemsetAsync(moe_acc, 0, (size_t)NTOK * D_DIM * sizeof(float), stream);
  hipMemsetAsync(counts, 0, (2 * NE) * sizeof(int) + NE * sizeof(float), stream);

  // attention
  k_rmsnorm<<<NTOK, 256, 0, stream>>>(x, g1, h);
  k_gemm<<<dim3(16, 32), 256, 0, stream>>>(h, wq, qb, nullptr, NTOK, HQn * HDn, D_DIM);
  k_gemm<<<dim3(4, 32), 256, 0, stream>>>(h, wk, kb, nullptr, NTOK, HKVn * HDn, D_DIM);
  k_gemm<<<dim3(4, 32), 256, 0, stream>>>(h, wv, vb, nullptr, NTOK, HKVn * HDn, D_DIM);
  k_rope<<<T_LEN, 256, 0, stream>>>(qb, kb);
  k_attn<<<dim3(T_LEN / 4, HQn), 256, 0, stream>>>(qb, kb, vb, ob);
  k_gemm<<<dim3(16, 32), 256, 0, stream>>>(ob, wo, x1, x, NTOK, D_DIM, D_DIM);

  // moe
  k_rmsnorm<<<NTOK, 256, 0, stream>>>(x1, g2, h);
  k_gate<<<NTOK / 4, 256, 0, stream>>>(h, gate_w, counts, ids, wts, load_sum);
  k_offsets<<<1, 1, 0, stream>>>(counts, offsets);
  k_moe_gateup<<<dim3(FF / 64, NTOK / 64, NE), 256, 0, stream>>>(h, we_gate, we_up, ids, wts,
                                                                 counts, offsets, act);
  k_moe_down<<<dim3(D_DIM / 64, NTOK / 64, NE), 256, 0, stream>>>(act, we_down, ids, counts,
                                                                  offsets, moe_acc);
  k_add<<<(NTOK * D_DIM) / (256 * 4), 256, 0, stream>>>(x1, moe_acc, out);
  k_aux<<<1, 1, 0, stream>>>(counts, load_sum, out + (size_t)NTOK * D_DIM);
}

// Round 3
// 1293.937 us; speedup vs baseline: 2.9352x; 2.9352x over previous
//
#include <hip/hip_runtime.h>
#include <cstdint>

typedef __attribute__((ext_vector_type(8))) short short8;
typedef __attribute__((ext_vector_type(4))) float floatx4;
typedef unsigned short ushort;

#define T_LEN 2048
#define D_DIM 1024
#define HQn 16
#define HKVn 4
#define HDn 64
#define NE 8
#define FF 2752
#define NTOK 2048
#define NSLOT 4096
#define ATT_SCALE 0.125f

__device__ inline ushort f2bf(float f) {
  union { float f; unsigned int i; } v; v.f = f;
  unsigned int r = v.i + 0x7fffu + ((v.i >> 16) & 1u);
  return (ushort)(r >> 16);
}
__device__ inline float bf2f(ushort h) {
  union { unsigned int i; float f; } v; v.i = ((unsigned int)h) << 16;
  return v.f;
}
__device__ inline void split8(const float* v, short8& hi, short8& lo) {
#pragma unroll
  for (int i = 0; i < 8; i++) {
    ushort h = f2bf(v[i]);
    hi[i] = (short)h;
    lo[i] = (short)f2bf(v[i] - bf2f(h));
  }
}
__device__ inline floatx4 mfma16(short8 a, short8 b, floatx4 c) {
  return __builtin_amdgcn_mfma_f32_16x16x32_bf16(a, b, c, 0, 0, 0);
}

// ---------------- transpose+convert fp32 -> bf16 [C][R] (batch z) ----------------
__global__ __launch_bounds__(256) void k_cvtT(const float* __restrict__ src,
                                              ushort* __restrict__ dst, int R, int C) {
  __shared__ float tile[32][33];
  size_t sb = (size_t)blockIdx.z * R * C;
  const float* s = src + sb;
  ushort* d = dst + sb;
  int r0 = blockIdx.y * 32, c0 = blockIdx.x * 32;
  int tc = threadIdx.x & 31, tr = threadIdx.x >> 5;
#pragma unroll
  for (int i = 0; i < 4; i++)
    tile[tr + i * 8][tc] = s[(size_t)(r0 + tr + i * 8) * C + c0 + tc];
  __syncthreads();
#pragma unroll
  for (int i = 0; i < 4; i++) {
    int cc = tr + i * 8;
    d[(size_t)(c0 + cc) * R + r0 + tc] = f2bf(tile[tc][cc]);
  }
}

// ---------------- transpose fp32 -> fp32 [C][R] ----------------
__global__ __launch_bounds__(256) void k_cvtTf(const float* __restrict__ src,
                                               float* __restrict__ dst, int R, int C) {
  __shared__ float tile[32][33];
  const float* s = src;
  float* d = dst;
  int r0 = blockIdx.y * 32, c0 = blockIdx.x * 32;
  int tc = threadIdx.x & 31, tr = threadIdx.x >> 5;
#pragma unroll
  for (int i = 0; i < 4; i++)
    tile[tr + i * 8][tc] = s[(size_t)(r0 + tr + i * 8) * C + c0 + tc];
  __syncthreads();
#pragma unroll
  for (int i = 0; i < 4; i++) {
    int cc = tr + i * 8;
    d[(size_t)(c0 + cc) * R + r0 + tc] = tile[tc][cc];
  }
}

// ---------------- RMSNorm fp32 -> fp32 ----------------
__global__ __launch_bounds__(256) void k_rmsnorm(const float* __restrict__ x,
                                                 const float* __restrict__ g,
                                                 float* __restrict__ out) {
  int row = blockIdx.x;
  int t = threadIdx.x;
  const float4* x4 = (const float4*)(x + (size_t)row * D_DIM);
  float4 v = x4[t];
  float ss = v.x * v.x + v.y * v.y + v.z * v.z + v.w * v.w;
#pragma unroll
  for (int off = 32; off; off >>= 1) ss += __shfl_xor(ss, off, 64);
  __shared__ float red[4];
  if ((t & 63) == 0) red[t >> 6] = ss;
  __syncthreads();
  float tot = red[0] + red[1] + red[2] + red[3];
  float sc = rsqrtf(tot * (1.0f / D_DIM) + 1e-6f);
  const float4* g4 = (const float4*)g;
  float4 gv = g4[t];
  float4 o;
  o.x = v.x * gv.x * sc;
  o.y = v.y * gv.y * sc;
  o.z = v.z * gv.z * sc;
  o.w = v.w * gv.w * sc;
  ((float4*)(out + (size_t)row * D_DIM))[t] = o;
}

// ------- split-bf16 (x3) emulated-fp32 MFMA GEMM: C = A[M,K] @ Bt[N,K]^T (+res) -------
__global__ __launch_bounds__(256) void k_sgemm(const float* __restrict__ A,
                                               const float* __restrict__ Bt,
                                               float* __restrict__ C,
                                               const float* __restrict__ res,
                                               int M, int N, int K) {
  __shared__ ushort Ah[128][40], Al[128][40], Bh[128][40], Bl[128][40];
  int tid = threadIdx.x;
  int m0 = blockIdx.y * 128, n0 = blockIdx.x * 128;
  int wave = tid >> 6, lane = tid & 63, quad = lane >> 4, l15 = lane & 15;
  int wm = (wave >> 1) * 64, wn = (wave & 1) * 64;
  int srow = tid >> 2, skc = (tid & 3) * 8;
  floatx4 acc[4][4];
#pragma unroll
  for (int i = 0; i < 4; i++)
#pragma unroll
    for (int j = 0; j < 4; j++) acc[i][j] = (floatx4){0.f, 0.f, 0.f, 0.f};
  const float* Ap0 = A + (size_t)(m0 + srow) * K + skc;
  const float* Ap1 = Ap0 + (size_t)64 * K;
  int bn0 = n0 + srow, bn1 = bn0 + 64;
  const float* Bp0 = Bt + (size_t)bn0 * K + skc;
  const float* Bp1 = Bt + (size_t)bn1 * K + skc;
  for (int k0 = 0; k0 < K; k0 += 32) {
    float va[8];
    short8 h8, l8;
    *(float4*)(va) = *(const float4*)(Ap0 + k0);
    *(float4*)(va + 4) = *(const float4*)(Ap0 + k0 + 4);
    split8(va, h8, l8);
    *(short8*)&Ah[srow][skc] = h8; *(short8*)&Al[srow][skc] = l8;
    *(float4*)(va) = *(const float4*)(Ap1 + k0);
    *(float4*)(va + 4) = *(const float4*)(Ap1 + k0 + 4);
    split8(va, h8, l8);
    *(short8*)&Ah[srow + 64][skc] = h8; *(short8*)&Al[srow + 64][skc] = l8;
    if (bn0 < N) {
      *(float4*)(va) = *(const float4*)(Bp0 + k0);
      *(float4*)(va + 4) = *(const float4*)(Bp0 + k0 + 4);
    } else {
#pragma unroll
      for (int i = 0; i < 8; i++) va[i] = 0.f;
    }
    split8(va, h8, l8);
    *(short8*)&Bh[srow][skc] = h8; *(short8*)&Bl[srow][skc] = l8;
    if (bn1 < N) {
      *(float4*)(va) = *(const float4*)(Bp1 + k0);
      *(float4*)(va + 4) = *(const float4*)(Bp1 + k0 + 4);
    } else {
#pragma unroll
      for (int i = 0; i < 8; i++) va[i] = 0.f;
    }
    split8(va, h8, l8);
    *(short8*)&Bh[srow + 64][skc] = h8; *(short8*)&Bl[srow + 64][skc] = l8;
    __syncthreads();
    short8 ah[4], al[4], bh[4], bl[4];
#pragma unroll
    for (int mt = 0; mt < 4; mt++) {
      ah[mt] = *(short8*)&Ah[wm + mt * 16 + l15][quad * 8];
      al[mt] = *(short8*)&Al[wm + mt * 16 + l15][quad * 8];
    }
#pragma unroll
    for (int nt = 0; nt < 4; nt++) {
      bh[nt] = *(short8*)&Bh[wn + nt * 16 + l15][quad * 8];
      bl[nt] = *(short8*)&Bl[wn + nt * 16 + l15][quad * 8];
    }
#pragma unroll
    for (int mt = 0; mt < 4; mt++)
#pragma unroll
      for (int nt = 0; nt < 4; nt++) {
        acc[mt][nt] = mfma16(ah[mt], bh[nt], acc[mt][nt]);
        acc[mt][nt] = mfma16(ah[mt], bl[nt], acc[mt][nt]);
        acc[mt][nt] = mfma16(al[mt], bh[nt], acc[mt][nt]);
      }
    __syncthreads();
  }
#pragma unroll
  for (int mt = 0; mt < 4; mt++) {
    int row = m0 + wm + mt * 16 + quad * 4;
#pragma unroll
    for (int nt = 0; nt < 4; nt++) {
      int col = n0 + wn + nt * 16 + l15;
      if (col < N) {
#pragma unroll
        for (int r = 0; r < 4; r++) {
          float v = acc[mt][nt][r];
          if (res) v += res[(size_t)(row + r) * N + col];
          C[(size_t)(row + r) * N + col] = v;
        }
      }
    }
  }
}

// ------- RoPE fp32: qkvf [T,1536] -> qbh [HQ][T][64], kbh [HKV][T][64] fp32 -------
__global__ __launch_bounds__(256) void k_rope_cvt(const float* __restrict__ qkvf,
                                                  float* __restrict__ qbh,
                                                  float* __restrict__ kbh) {
  int t = blockIdx.x;
  const float* row = qkvf + (size_t)t * 1536;
  for (int it = threadIdx.x; it < (HQn + HKVn) * 32; it += 256) {
    int hh = it >> 5, i = it & 31;
    float inv = powf(10000.0f, -(float)i / 32.0f);
    float ang = (float)t * inv;
    float c = cosf(ang), s = sinf(ang);
    const float* p;
    float* dst;
    if (hh < HQn) {
      p = row + hh * 64;
      dst = qbh + ((size_t)hh * T_LEN + t) * 64;
    } else {
      int h2 = hh - HQn;
      p = row + 1024 + h2 * 64;
      dst = kbh + ((size_t)h2 * T_LEN + t) * 64;
    }
    float a = p[i], b = p[i + 32];
    dst[i] = a * c - b * s;
    dst[i + 32] = b * c + a * s;
  }
}

// ---------------- V transpose fp32: qkvf v-part -> vbt [HKV*64][T] ----------------
__global__ __launch_bounds__(256) void k_vT(const float* __restrict__ qkvf,
                                            float* __restrict__ vbt) {
  __shared__ float tile[32][33];
  int t0 = blockIdx.x * 32;
  int dh = blockIdx.y;
  int col0 = 1280 + dh * 32;
  int tc = threadIdx.x & 31, tr = threadIdx.x >> 5;
#pragma unroll
  for (int i = 0; i < 4; i++)
    tile[tr + i * 8][tc] = qkvf[(size_t)(t0 + tr + i * 8) * 1536 + col0 + tc];
  __syncthreads();
#pragma unroll
  for (int i = 0; i < 4; i++) {
    int dd = tr + i * 8;
    vbt[(size_t)(dh * 32 + dd) * T_LEN + t0 + tc] = tile[tc][dd];
  }
}

// ------- split-bf16 MFMA flash attention: 64 q-rows/block, fp32-accurate -------
__global__ __launch_bounds__(256) void k_attn(const float* __restrict__ qbh,
                                              const float* __restrict__ kbh,
                                              const float* __restrict__ vbt,
                                              float* __restrict__ ob) {
  __shared__ ushort Kh[64][72], Kl[64][72], Vh[64][72], Vl[64][72];
  __shared__ ushort Psh[4][16][72], Psl[4][16][72];
  int qh = blockIdx.y, kvh = qh >> 2;
  int r0 = blockIdx.x * 64;
  int tid = threadIdx.x, wave = tid >> 6, lane = tid & 63;
  int quad = lane >> 4, l15 = lane & 15;
  // stage Q through K buffers, grab fragments into registers
#pragma unroll
  for (int it = 0; it < 2; it++) {
    int c = tid + it * 256;
    int row = c >> 3, col = (c & 7) * 8;
    float va[8];
    short8 h8, l8;
    const float* src = qbh + ((size_t)qh * T_LEN + r0 + row) * 64 + col;
    *(float4*)(va) = *(const float4*)(src);
    *(float4*)(va + 4) = *(const float4*)(src + 4);
    split8(va, h8, l8);
    *(short8*)&Kh[row][col] = h8;
    *(short8*)&Kl[row][col] = l8;
  }
  __syncthreads();
  short8 aqh0 = *(short8*)&Kh[wave * 16 + l15][quad * 8];
  short8 aqh1 = *(short8*)&Kh[wave * 16 + l15][32 + quad * 8];
  short8 aql0 = *(short8*)&Kl[wave * 16 + l15][quad * 8];
  short8 aql1 = *(short8*)&Kl[wave * 16 + l15][32 + quad * 8];
  floatx4 oacc[4];
#pragma unroll
  for (int nt = 0; nt < 4; nt++) oacc[nt] = (floatx4){0.f, 0.f, 0.f, 0.f};
  float mrun[4], lrun[4];
#pragma unroll
  for (int r = 0; r < 4; r++) { mrun[r] = -INFINITY; lrun[r] = 0.f; }
  int cq = r0 >> 6;
  for (int cc = 0; cc <= cq; cc++) {
    __syncthreads();
#pragma unroll
    for (int it = 0; it < 2; it++) {
      int c = tid + it * 256;
      int row = c >> 3, col = (c & 7) * 8;
      float va[8];
      short8 h8, l8;
      const float* ks = kbh + ((size_t)kvh * T_LEN + cc * 64 + row) * 64 + col;
      *(float4*)(va) = *(const float4*)(ks);
      *(float4*)(va + 4) = *(const float4*)(ks + 4);
      split8(va, h8, l8);
      *(short8*)&Kh[row][col] = h8;
      *(short8*)&Kl[row][col] = l8;
      const float* vs = vbt + ((size_t)(kvh * 64 + row)) * T_LEN + cc * 64 + col;
      *(float4*)(va) = *(const float4*)(vs);
      *(float4*)(va + 4) = *(const float4*)(vs + 4);
      split8(va, h8, l8);
      *(short8*)&Vh[row][col] = h8;
      *(short8*)&Vl[row][col] = l8;
    }
    __syncthreads();
    floatx4 s[4];
#pragma unroll
    for (int nt = 0; nt < 4; nt++) {
      short8 bh0 = *(short8*)&Kh[nt * 16 + l15][quad * 8];
      short8 bh1 = *(short8*)&Kh[nt * 16 + l15][32 + quad * 8];
      short8 bl0 = *(short8*)&Kl[nt * 16 + l15][quad * 8];
      short8 bl1 = *(short8*)&Kl[nt * 16 + l15][32 + quad * 8];
      floatx4 z = (floatx4){0.f, 0.f, 0.f, 0.f};
      z = mfma16(aqh0, bh0, z);
      z = mfma16(aqh1, bh1, z);
      z = mfma16(aqh0, bl0, z);
      z = mfma16(aqh1, bl1, z);
      z = mfma16(aql0, bh0, z);
      z = mfma16(aql1, bh1, z);
      s[nt] = z;
    }
    int rowg0 = r0 + wave * 16 + quad * 4;
#pragma unroll
    for (int nt = 0; nt < 4; nt++) {
      int colg = cc * 64 + nt * 16 + l15;
#pragma unroll
      for (int r = 0; r < 4; r++) {
        float v = s[nt][r] * ATT_SCALE;
        s[nt][r] = (colg > rowg0 + r) ? -INFINITY : v;
      }
    }
    float mnew[4], alpha[4], psum[4];
#pragma unroll
    for (int r = 0; r < 4; r++) {
      float mx = fmaxf(fmaxf(s[0][r], s[1][r]), fmaxf(s[2][r], s[3][r]));
#pragma unroll
      for (int off = 1; off < 16; off <<= 1) mx = fmaxf(mx, __shfl_xor(mx, off, 64));
      mnew[r] = fmaxf(mrun[r], mx);
      psum[r] = 0.f;
    }
#pragma unroll
    for (int nt = 0; nt < 4; nt++)
#pragma unroll
      for (int r = 0; r < 4; r++) {
        float p = __expf(s[nt][r] - mnew[r]);
        s[nt][r] = p;
        psum[r] += p;
      }
#pragma unroll
    for (int r = 0; r < 4; r++) {
      float ps = psum[r];
#pragma unroll
      for (int off = 1; off < 16; off <<= 1) ps += __shfl_xor(ps, off, 64);
      alpha[r] = __expf(mrun[r] - mnew[r]);
      lrun[r] = lrun[r] * alpha[r] + ps;
      mrun[r] = mnew[r];
    }
#pragma unroll
    for (int nt = 0; nt < 4; nt++)
#pragma unroll
      for (int r = 0; r < 4; r++) oacc[nt][r] *= alpha[r];
#pragma unroll
    for (int nt = 0; nt < 4; nt++)
#pragma unroll
      for (int r = 0; r < 4; r++) {
        float p = s[nt][r];
        ushort ph = f2bf(p);
        Psh[wave][quad * 4 + r][nt * 16 + l15] = ph;
        Psl[wave][quad * 4 + r][nt * 16 + l15] = f2bf(p - bf2f(ph));
      }
    short8 aph0 = *(short8*)&Psh[wave][l15][quad * 8];
    short8 aph1 = *(short8*)&Psh[wave][l15][32 + quad * 8];
    short8 apl0 = *(short8*)&Psl[wave][l15][quad * 8];
    short8 apl1 = *(short8*)&Psl[wave][l15][32 + quad * 8];
#pragma unroll
    for (int nt = 0; nt < 4; nt++) {
      short8 bvh0 = *(short8*)&Vh[nt * 16 + l15][quad * 8];
      short8 bvh1 = *(short8*)&Vh[nt * 16 + l15][32 + quad * 8];
      short8 bvl0 = *(short8*)&Vl[nt * 16 + l15][quad * 8];
      short8 bvl1 = *(short8*)&Vl[nt * 16 + l15][32 + quad * 8];
      oacc[nt] = mfma16(aph0, bvh0, oacc[nt]);
      oacc[nt] = mfma16(aph1, bvh1, oacc[nt]);
      oacc[nt] = mfma16(aph0, bvl0, oacc[nt]);
      oacc[nt] = mfma16(aph1, bvl1, oacc[nt]);
      oacc[nt] = mfma16(apl0, bvh0, oacc[nt]);
      oacc[nt] = mfma16(apl1, bvh1, oacc[nt]);
    }
  }
#pragma unroll
  for (int nt = 0; nt < 4; nt++)
#pragma unroll
    for (int r = 0; r < 4; r++) {
      int rowg = r0 + wave * 16 + quad * 4 + r;
      ob[(size_t)rowg * D_DIM + qh * 64 + nt * 16 + l15] = oacc[nt][r] / lrun[r];
    }
}

// ------- gate: exact fp32 rmsnorm + logits, top-2 picked on raw logits -------
__global__ __launch_bounds__(256) void k_gate(const float* __restrict__ x1,
                                              const float* __restrict__ g2,
                                              const float* __restrict__ gw,
                                              int* __restrict__ counts,
                                              int* __restrict__ ids,
                                              float* __restrict__ wts,
                                              float* __restrict__ load_sum) {
  int wave = threadIdx.x >> 6, lane = threadIdx.x & 63;
  int token = blockIdx.x * 4 + wave;
  const float* xp = x1 + (size_t)token * D_DIM;
  float acc[NE] = {};
  float ss = 0.f;
  for (int d = lane; d < D_DIM; d += 64) {
    float xv = xp[d];
    ss += xv * xv;
    float hv = xv * g2[d];
#pragma unroll
    for (int e = 0; e < NE; e++) acc[e] += hv * gw[d * NE + e];
  }
#pragma unroll
  for (int off = 32; off; off >>= 1) ss += __shfl_xor(ss, off, 64);
#pragma unroll
  for (int e = 0; e < NE; e++)
#pragma unroll
    for (int off = 32; off; off >>= 1) acc[e] += __shfl_xor(acc[e], off, 64);
  if (lane == 0) {
    float sc = rsqrtf(ss * (1.0f / D_DIM) + 1e-6f);
    float mx = -1e30f;
#pragma unroll
    for (int e = 0; e < NE; e++) { acc[e] *= sc; mx = fmaxf(mx, acc[e]); }
    float p[NE], sum = 0.f;
#pragma unroll
    for (int e = 0; e < NE; e++) { p[e] = expf(acc[e] - mx); sum += p[e]; }
#pragma unroll
    for (int e = 0; e < NE; e++) p[e] /= sum;
    int i1 = 0;
#pragma unroll
    for (int e = 1; e < NE; e++) if (acc[e] > acc[i1]) i1 = e;
    int i2 = (i1 == 0) ? 1 : 0;
#pragma unroll
    for (int e = 0; e < NE; e++) if (e != i1 && acc[e] > acc[i2]) i2 = e;
    float denom = p[i1] + p[i2] + 1e-8f;
    int pos = atomicAdd(&counts[i1], 1);
    ids[i1 * NTOK + pos] = token;
    wts[i1 * NTOK + pos] = p[i1] / denom;
    pos = atomicAdd(&counts[i2], 1);
    ids[i2 * NTOK + pos] = token;
    wts[i2 * NTOK + pos] = p[i2] / denom;
#pragma unroll
    for (int e = 0; e < NE; e++) atomicAdd(&load_sum[e], p[e]);
  }
}

__global__ void k_offsets(const int* __restrict__ counts, int* __restrict__ offsets) {
  if (threadIdx.x == 0 && blockIdx.x == 0) {
    int s = 0;
    for (int e = 0; e < NE; e++) { offsets[e] = s; s += counts[e]; }
  }
}

// ---------------- MoE gate/up bf16 MFMA GEMM + SiLU*up*w -> act bf16 ----------------
__global__ __launch_bounds__(256) void k_moe_gateup(const float* __restrict__ h,
                                                    const ushort* __restrict__ wgT,
                                                    const ushort* __restrict__ wuT,
                                                    const int* __restrict__ ids,
                                                    const float* __restrict__ wts,
                                                    const int* __restrict__ counts,
                                                    const int* __restrict__ offsets,
                                                    ushort* __restrict__ act) {
  int e = blockIdx.z;
  int cnt = counts[e];
  int m0 = blockIdx.y * 128;
  if (m0 >= cnt) return;
  int n0 = blockIdx.x * 128;
  __shared__ ushort As[128][40];
  __shared__ ushort Bg[128][40];
  __shared__ ushort Bu[128][40];
  __shared__ int toks[128];
  __shared__ float wrow[128];
  int tid = threadIdx.x;
  if (tid < 128) {
    int mm = m0 + tid;
    toks[tid] = (mm < cnt) ? ids[e * NTOK + mm] : 0;
    wrow[tid] = (mm < cnt) ? wts[e * NTOK + mm] : 0.f;
  }
  __syncthreads();
  int wave = tid >> 6, lane = tid & 63, quad = lane >> 4, l15 = lane & 15;
  int wm = (wave >> 1) * 64, wn = (wave & 1) * 64;
  int srow = tid >> 2, skc = (tid & 3) * 8;
  int tok0 = toks[srow], tok1 = toks[srow + 64];
  floatx4 accg[4][4], accu[4][4];
#pragma unroll
  for (int i = 0; i < 4; i++)
#pragma unroll
    for (int j = 0; j < 4; j++) {
      accg[i][j] = (floatx4){0.f, 0.f, 0.f, 0.f};
      accu[i][j] = (floatx4){0.f, 0.f, 0.f, 0.f};
    }
  const ushort* Wg = wgT + (size_t)e * FF * D_DIM;
  const ushort* Wu = wuT + (size_t)e * FF * D_DIM;
  int bn0 = n0 + srow, bn1 = n0 + srow + 64;
  bool v0 = bn0 < FF, v1 = bn1 < FF;
  const float* Ap0 = h + (size_t)tok0 * D_DIM + skc;
  const float* Ap1 = h + (size_t)tok1 * D_DIM + skc;
  const ushort* Bg0 = Wg + (size_t)bn0 * D_DIM + skc;
  const ushort* Bg1 = Wg + (size_t)bn1 * D_DIM + skc;
  const ushort* Bu0 = Wu + (size_t)bn0 * D_DIM + skc;
  const ushort* Bu1 = Wu + (size_t)bn1 * D_DIM + skc;
  short8 zero8 = {0, 0, 0, 0, 0, 0, 0, 0};
  for (int k0 = 0; k0 < D_DIM; k0 += 32) {
    float va[8];
    short8 a8;
    *(float4*)(va) = *(const float4*)(Ap0 + k0);
    *(float4*)(va + 4) = *(const float4*)(Ap0 + k0 + 4);
#pragma unroll
    for (int i = 0; i < 8; i++) a8[i] = (short)f2bf(va[i]);
    *(short8*)&As[srow][skc] = a8;
    *(float4*)(va) = *(const float4*)(Ap1 + k0);
    *(float4*)(va + 4) = *(const float4*)(Ap1 + k0 + 4);
#pragma unroll
    for (int i = 0; i < 8; i++) a8[i] = (short)f2bf(va[i]);
    *(short8*)&As[srow + 64][skc] = a8;
    *(short8*)&Bg[srow][skc] = v0 ? *(const short8*)(Bg0 + k0) : zero8;
    *(short8*)&Bg[srow + 64][skc] = v1 ? *(const short8*)(Bg1 + k0) : zero8;
    *(short8*)&Bu[srow][skc] = v0 ? *(const short8*)(Bu0 + k0) : zero8;
    *(short8*)&Bu[srow + 64][skc] = v1 ? *(const short8*)(Bu1 + k0) : zero8;
    __syncthreads();
    short8 aF[4], gF[4], uF[4];
#pragma unroll
    for (int mt = 0; mt < 4; mt++) aF[mt] = *(short8*)&As[wm + mt * 16 + l15][quad * 8];
#pragma unroll
    for (int nt = 0; nt < 4; nt++) {
      gF[nt] = *(short8*)&Bg[wn + nt * 16 + l15][quad * 8];
      uF[nt] = *(short8*)&Bu[wn + nt * 16 + l15][quad * 8];
    }
#pragma unroll
    for (int mt = 0; mt < 4; mt++)
#pragma unroll
      for (int nt = 0; nt < 4; nt++) {
        accg[mt][nt] = mfma16(aF[mt], gF[nt], accg[mt][nt]);
        accu[mt][nt] = mfma16(aF[mt], uF[nt], accu[mt][nt]);
      }
    __syncthreads();
  }
  int aoff = offsets[e];
#pragma unroll
  for (int mt = 0; mt < 4; mt++) {
    int mrow = wm + mt * 16 + quad * 4;
#pragma unroll
    for (int nt = 0; nt < 4; nt++) {
      int col = n0 + wn + nt * 16 + l15;
      if (col < FF) {
#pragma unroll
        for (int r = 0; r < 4; r++) {
          int ml = mrow + r;
          if (m0 + ml < cnt) {
            float g = accg[mt][nt][r];
            float u = accu[mt][nt][r];
            float sil = g / (1.f + __expf(-g));
            act[(size_t)(aoff + m0 + ml) * FF + col] = f2bf(sil * u * wrow[ml]);
          }
        }
      }
    }
  }
}

// ---------------- MoE down bf16 MFMA GEMM, scatter-add ----------------
__global__ __launch_bounds__(256) void k_moe_down(const ushort* __restrict__ act,
                                                  const ushort* __restrict__ wdT,
                                                  const int* __restrict__ ids,
                                                  const int* __restrict__ counts,
                                                  const int* __restrict__ offsets,
                                                  float* __restrict__ moe_acc) {
  int e = blockIdx.z;
  int cnt = counts[e];
  int m0 = blockIdx.y * 128;
  if (m0 >= cnt) return;
  int n0 = blockIdx.x * 128;
  __shared__ ushort As[128][40];
  __shared__ ushort Bs[128][40];
  __shared__ int toks[128];
  int tid = threadIdx.x;
  if (tid < 128) {
    int mm = m0 + tid;
    toks[tid] = (mm < cnt) ? ids[e * NTOK + mm] : 0;
  }
  __syncthreads();
  int wave = tid >> 6, lane = tid & 63, quad = lane >> 4, l15 = lane & 15;
  int wm = (wave >> 1) * 64, wn = (wave & 1) * 64;
  int srow = tid >> 2, skc = (tid & 3) * 8;
  floatx4 acc[4][4];
#pragma unroll
  for (int i = 0; i < 4; i++)
#pragma unroll
    for (int j = 0; j < 4; j++) acc[i][j] = (floatx4){0.f, 0.f, 0.f, 0.f};
  int aoff = offsets[e];
  const ushort* Ap0 = act + (size_t)(aoff + m0 + srow) * FF + skc;
  const ushort* Ap1 = act + (size_t)(aoff + m0 + srow + 64) * FF + skc;
  const ushort* Wd = wdT + (size_t)e * D_DIM * FF;
  const ushort* Bp0 = Wd + (size_t)(n0 + srow) * FF + skc;
  const ushort* Bp1 = Wd + (size_t)(n0 + srow + 64) * FF + skc;
  for (int k0 = 0; k0 < FF; k0 += 32) {
    *(short8*)&As[srow][skc] = *(const short8*)(Ap0 + k0);
    *(short8*)&As[srow + 64][skc] = *(const short8*)(Ap1 + k0);
    *(short8*)&Bs[srow][skc] = *(const short8*)(Bp0 + k0);
    *(short8*)&Bs[srow + 64][skc] = *(const short8*)(Bp1 + k0);
    __syncthreads();
    short8 aF[4], bF[4];
#pragma unroll
    for (int mt = 0; mt < 4; mt++) aF[mt] = *(short8*)&As[wm + mt * 16 + l15][quad * 8];
#pragma unroll
    for (int nt = 0; nt < 4; nt++) bF[nt] = *(short8*)&Bs[wn + nt * 16 + l15][quad * 8];
#pragma unroll
    for (int mt = 0; mt < 4; mt++)
#pragma unroll
      for (int nt = 0; nt < 4; nt++) acc[mt][nt] = mfma16(aF[mt], bF[nt], acc[mt][nt]);
    __syncthreads();
  }
#pragma unroll
  for (int mt = 0; mt < 4; mt++) {
    int mrow = wm + mt * 16 + quad * 4;
#pragma unroll
    for (int nt = 0; nt < 4; nt++) {
      int col = n0 + wn + nt * 16 + l15;
#pragma unroll
      for (int r = 0; r < 4; r++) {
        int ml = mrow + r;
        if (m0 + ml < cnt)
          atomicAdd(&moe_acc[(size_t)toks[ml] * D_DIM + col], acc[mt][nt][r]);
      }
    }
  }
}

__global__ __launch_bounds__(256) void k_add(const float* __restrict__ a,
                                             const float* __restrict__ b,
                                             float* __restrict__ o) {
  int i = blockIdx.x * 256 + threadIdx.x;
  float4 va = ((const float4*)a)[i];
  float4 vb = ((const float4*)b)[i];
  float4 vo;
  vo.x = va.x + vb.x; vo.y = va.y + vb.y; vo.z = va.z + vb.z; vo.w = va.w + vb.w;
  ((float4*)o)[i] = vo;
}

__global__ void k_aux(const int* __restrict__ counts, const float* __restrict__ load_sum,
                      float* __restrict__ out_aux) {
  if (threadIdx.x == 0 && blockIdx.x == 0) {
    float s = 0.f;
    for (int e = 0; e < NE; e++)
      s += ((float)counts[e] / (float)NSLOT) * (load_sum[e] / (float)NTOK);
    *out_aux = 0.01f * (float)NE * s;
  }
}

extern "C" void kernel_launch(void* const* d_in, const int* in_sizes, int n_in,
                              void* d_out, int out_size, void* d_ws, size_t ws_size,
                              hipStream_t stream) {
  const float* x = (const float*)d_in[0];
  const float* g1 = (const float*)d_in[1];
  const float* g2 = (const float*)d_in[2];
  const float* wq = (const float*)d_in[3];
  const float* wk = (const float*)d_in[4];
  const float* wv = (const float*)d_in[5];
  const float* wo = (const float*)d_in[6];
  const float* gate_w = (const float*)d_in[7];
  const float* we_gate = (const float*)d_in[8];
  const float* we_up = (const float*)d_in[9];
  const float* we_down = (const float*)d_in[10];
  float* out = (float*)d_out;

  char* w = (char*)d_ws;
  size_t o = 0;
  auto alloc = [&](size_t bytes) -> char* {
    char* p = w + o;
    o = (o + bytes + 255) & ~(size_t)255;
    return p;
  };
  float* h = (float*)alloc((size_t)NTOK * D_DIM * 4);
  float* qkvf = (float*)alloc((size_t)NTOK * 1536 * 4);
  float* qbh = (float*)alloc((size_t)HQn * T_LEN * 64 * 4);
  float* kbh = (float*)alloc((size_t)HKVn * T_LEN * 64 * 4);
  float* vbt = (float*)alloc((size_t)HKVn * 64 * T_LEN * 4);
  float* ob = (float*)alloc((size_t)NTOK * D_DIM * 4);
  float* x1 = (float*)alloc((size_t)NTOK * D_DIM * 4);
  float* moe_acc = (float*)alloc((size_t)NTOK * D_DIM * 4);
  ushort* act = (ushort*)alloc((size_t)(NSLOT + 128) * FF * 2);
  float* qkvwTf = (float*)alloc((size_t)1536 * 1024 * 4);
  float* woTf = (float*)alloc((size_t)1024 * 1024 * 4);
  ushort* wgT = (ushort*)alloc((size_t)NE * FF * D_DIM * 2);
  ushort* wuT = (ushort*)alloc((size_t)NE * FF * D_DIM * 2);
  ushort* wdT = (ushort*)alloc((size_t)NE * D_DIM * FF * 2);
  int* counts = (int*)alloc(NE * 4);
  int* offsets = (int*)alloc(NE * 4);
  float* load_sum = (float*)alloc(NE * 4);
  int* ids = (int*)alloc((size_t)NE * NTOK * 4);
  float* wts = (float*)alloc((size_t)NE * NTOK * 4);

  hipMemsetAsync(moe_acc, 0, (size_t)NTOK * D_DIM * 4, stream);
  hipMemsetAsync(counts, 0, 768, stream);  // counts+offsets+load_sum slots

  // weight transposes (fp32 for attention path, bf16 for experts)
  k_cvtTf<<<dim3(32, 32), 256, 0, stream>>>(wq, qkvwTf, 1024, 1024);
  k_cvtTf<<<dim3(8, 32), 256, 0, stream>>>(wk, qkvwTf + (size_t)1024 * 1024, 1024, 256);
  k_cvtTf<<<dim3(8, 32), 256, 0, stream>>>(wv, qkvwTf + (size_t)1280 * 1024, 1024, 256);
  k_cvtTf<<<dim3(32, 32), 256, 0, stream>>>(wo, woTf, 1024, 1024);
  k_cvtT<<<dim3(86, 32, 8), 256, 0, stream>>>(we_gate, wgT, 1024, 2752);
  k_cvtT<<<dim3(86, 32, 8), 256, 0, stream>>>(we_up, wuT, 1024, 2752);
  k_cvtT<<<dim3(32, 86, 8), 256, 0, stream>>>(we_down, wdT, 2752, 1024);

  // attention path (fp32-accurate via split-bf16 MFMA)
  k_rmsnorm<<<NTOK, 256, 0, stream>>>(x, g1, h);
  k_sgemm<<<dim3(12, 16), 256, 0, stream>>>(h, qkvwTf, qkvf, nullptr, NTOK, 1536, 1024);
  k_rope_cvt<<<T_LEN, 256, 0, stream>>>(qkvf, qbh, kbh);
  k_vT<<<dim3(64, 8), 256, 0, stream>>>(qkvf, vbt);
  k_attn<<<dim3(32, 16), 256, 0, stream>>>(qbh, kbh, vbt, ob);
  k_sgemm<<<dim3(8, 16), 256, 0, stream>>>(ob, woTf, x1, x, NTOK, 1024, 1024);

  // moe
  k_rmsnorm<<<NTOK, 256, 0, stream>>>(x1, g2, h);
  k_gate<<<NTOK / 4, 256, 0, stream>>>(x1, g2, gate_w, counts, ids, wts, load_sum);
  k_offsets<<<1, 1, 0, stream>>>(counts, offsets);
  k_moe_gateup<<<dim3(22, 16, 8), 256, 0, stream>>>(h, wgT, wuT, ids, wts, counts,
                                                    offsets, act);
  k_moe_down<<<dim3(8, 16, 8), 256, 0, stream>>>(act, wdT, ids, counts, offsets, moe_acc);
  k_add<<<(NTOK * D_DIM) / (256 * 4), 256, 0, stream>>>(x1, moe_acc, out);
  k_aux<<<1, 1, 0, stream>>>(counts, load_sum, out + (size_t)NTOK * D_DIM);
}

// Round 4
// 1162.080 us; speedup vs baseline: 3.2682x; 1.1135x over previous
//
#include <hip/hip_runtime.h>
#include <cstdint>

typedef __attribute__((ext_vector_type(8))) short short8;
typedef __attribute__((ext_vector_type(4))) float floatx4;
typedef __attribute__((ext_vector_type(4))) unsigned short ushort4v;
typedef unsigned short ushort;

#define T_LEN 2048
#define D_DIM 1024
#define HQn 16
#define HKVn 4
#define NE 8
#define FF 2752
#define NTOK 2048
#define NSLOT 4096
#define ATT_SCALE 0.125f

__device__ inline ushort f2bf(float f) {
  union { float f; unsigned int i; } v; v.f = f;
  unsigned int r = v.i + 0x7fffu + ((v.i >> 16) & 1u);
  return (ushort)(r >> 16);
}
__device__ inline float bf2f(ushort h) {
  union { unsigned int i; float f; } v; v.i = ((unsigned int)h) << 16;
  return v.f;
}
__device__ inline void split8(const float* v, short8& hi, short8& lo) {
#pragma unroll
  for (int i = 0; i < 8; i++) {
    ushort h = f2bf(v[i]);
    hi[i] = (short)h;
    lo[i] = (short)f2bf(v[i] - bf2f(h));
  }
}
__device__ inline floatx4 mfma16(short8 a, short8 b, floatx4 c) {
  return __builtin_amdgcn_mfma_f32_16x16x32_bf16(a, b, c, 0, 0, 0);
}
// async global->LDS, 16B per lane; LDS dest = wave-uniform base + lane*16
#define DMA16(g, l)                                                              \
  __builtin_amdgcn_global_load_lds((const __attribute__((address_space(1))) void*)(g), \
                                   (__attribute__((address_space(3))) void*)(l), 16, 0, 0)

// ---------------- transpose+convert fp32 -> bf16 [C][R] (batch z) ----------------
__global__ __launch_bounds__(256) void k_cvtT(const float* __restrict__ src,
                                              ushort* __restrict__ dst, int R, int C) {
  __shared__ float tile[32][33];
  size_t sb = (size_t)blockIdx.z * R * C;
  const float* s = src + sb;
  ushort* d = dst + sb;
  int r0 = blockIdx.y * 32, c0 = blockIdx.x * 32;
  int tc = threadIdx.x & 31, tr = threadIdx.x >> 5;
#pragma unroll
  for (int i = 0; i < 4; i++)
    tile[tr + i * 8][tc] = s[(size_t)(r0 + tr + i * 8) * C + c0 + tc];
  __syncthreads();
#pragma unroll
  for (int i = 0; i < 4; i++) {
    int cc = tr + i * 8;
    d[(size_t)(c0 + cc) * R + r0 + tc] = f2bf(tile[tc][cc]);
  }
}

// ---------------- transpose+split fp32 -> hi/lo bf16 [C][R] ----------------
__global__ __launch_bounds__(256) void k_cvtT2(const float* __restrict__ src,
                                               ushort* __restrict__ dh,
                                               ushort* __restrict__ dl, int R, int C) {
  __shared__ float tile[32][33];
  int r0 = blockIdx.y * 32, c0 = blockIdx.x * 32;
  int tc = threadIdx.x & 31, tr = threadIdx.x >> 5;
#pragma unroll
  for (int i = 0; i < 4; i++)
    tile[tr + i * 8][tc] = src[(size_t)(r0 + tr + i * 8) * C + c0 + tc];
  __syncthreads();
#pragma unroll
  for (int i = 0; i < 4; i++) {
    int cc = tr + i * 8;
    float v = tile[tc][cc];
    ushort h = f2bf(v);
    dh[(size_t)(c0 + cc) * R + r0 + tc] = h;
    dl[(size_t)(c0 + cc) * R + r0 + tc] = f2bf(v - bf2f(h));
  }
}

// ---------------- RMSNorm fp32 -> hi/lo bf16 split ----------------
__global__ __launch_bounds__(256) void k_rmsnorm2(const float* __restrict__ x,
                                                  const float* __restrict__ g,
                                                  ushort* __restrict__ oh,
                                                  ushort* __restrict__ ol) {
  int row = blockIdx.x;
  int t = threadIdx.x;
  const float4* x4 = (const float4*)(x + (size_t)row * D_DIM);
  float4 v = x4[t];
  float ss = v.x * v.x + v.y * v.y + v.z * v.z + v.w * v.w;
#pragma unroll
  for (int off = 32; off; off >>= 1) ss += __shfl_xor(ss, off, 64);
  __shared__ float red[4];
  if ((t & 63) == 0) red[t >> 6] = ss;
  __syncthreads();
  float tot = red[0] + red[1] + red[2] + red[3];
  float sc = rsqrtf(tot * (1.0f / D_DIM) + 1e-6f);
  const float4* g4 = (const float4*)g;
  float4 gv = g4[t];
  float vals[4] = {v.x * gv.x * sc, v.y * gv.y * sc, v.z * gv.z * sc, v.w * gv.w * sc};
  ushort4v h4, l4;
#pragma unroll
  for (int i = 0; i < 4; i++) {
    ushort h = f2bf(vals[i]);
    h4[i] = h;
    l4[i] = f2bf(vals[i] - bf2f(h));
  }
  *(ushort4v*)(oh + (size_t)row * D_DIM + t * 4) = h4;
  *(ushort4v*)(ol + (size_t)row * D_DIM + t * 4) = l4;
}

// ------- split-bf16 emulated-fp32 MFMA GEMM (DMA-staged): C = A @ Bt^T (+res) -------
// A,B pre-split hi/lo bf16, A [M][K] rows, Bt [N][K] rows. M=2048 via grid, N%128==0.
__global__ __launch_bounds__(256) void k_sgemm(const ushort* __restrict__ Ahg,
                                               const ushort* __restrict__ Alg,
                                               const ushort* __restrict__ Bhg,
                                               const ushort* __restrict__ Blg,
                                               float* __restrict__ C,
                                               const float* __restrict__ res,
                                               int N, int K) {
  __shared__ __align__(16) ushort Ah[4096], Al[4096], Bh[4096], Bl[4096];
  int tid = threadIdx.x;
  int m0 = blockIdx.y * 128, n0 = blockIdx.x * 128;
  int wave = tid >> 6, lane = tid & 63, quad = lane >> 4, l15 = lane & 15;
  int wm = (wave >> 1) * 64, wn = (wave & 1) * 64;
  floatx4 acc[4][4];
#pragma unroll
  for (int i = 0; i < 4; i++)
#pragma unroll
    for (int j = 0; j < 4; j++) acc[i][j] = (floatx4){0.f, 0.f, 0.f, 0.f};
  const ushort *sAh[2], *sAl[2], *sBh[2], *sBl[2];
  int dof[2];
#pragma unroll
  for (int j = 0; j < 2; j++) {
    int u = (wave * 2 + j) * 64 + lane;
    int chunk = u >> 7, row = u & 127;
    sAh[j] = Ahg + (size_t)(m0 + row) * K + chunk * 8;
    sAl[j] = Alg + (size_t)(m0 + row) * K + chunk * 8;
    sBh[j] = Bhg + (size_t)(n0 + row) * K + chunk * 8;
    sBl[j] = Blg + (size_t)(n0 + row) * K + chunk * 8;
    dof[j] = (wave * 2 + j) * 512;
  }
  for (int k0 = 0; k0 < K; k0 += 32) {
#pragma unroll
    for (int j = 0; j < 2; j++) {
      DMA16(sAh[j] + k0, Ah + dof[j]);
      DMA16(sAl[j] + k0, Al + dof[j]);
      DMA16(sBh[j] + k0, Bh + dof[j]);
      DMA16(sBl[j] + k0, Bl + dof[j]);
    }
    __syncthreads();
    short8 ah[4], al[4], bh[4], bl[4];
#pragma unroll
    for (int mt = 0; mt < 4; mt++) {
      int ar = wm + mt * 16 + l15;
      ah[mt] = *(short8*)&Ah[quad * 1024 + ar * 8];
      al[mt] = *(short8*)&Al[quad * 1024 + ar * 8];
    }
#pragma unroll
    for (int nt = 0; nt < 4; nt++) {
      int br = wn + nt * 16 + l15;
      bh[nt] = *(short8*)&Bh[quad * 1024 + br * 8];
      bl[nt] = *(short8*)&Bl[quad * 1024 + br * 8];
    }
#pragma unroll
    for (int mt = 0; mt < 4; mt++)
#pragma unroll
      for (int nt = 0; nt < 4; nt++) {
        acc[mt][nt] = mfma16(ah[mt], bh[nt], acc[mt][nt]);
        acc[mt][nt] = mfma16(ah[mt], bl[nt], acc[mt][nt]);
        acc[mt][nt] = mfma16(al[mt], bh[nt], acc[mt][nt]);
      }
    __syncthreads();
  }
#pragma unroll
  for (int mt = 0; mt < 4; mt++) {
    int row = m0 + wm + mt * 16 + quad * 4;
#pragma unroll
    for (int nt = 0; nt < 4; nt++) {
      int col = n0 + wn + nt * 16 + l15;
#pragma unroll
      for (int r = 0; r < 4; r++) {
        float v = acc[mt][nt][r];
        if (res) v += res[(size_t)(row + r) * N + col];
        C[(size_t)(row + r) * N + col] = v;
      }
    }
  }
}

// ------- RoPE fp32: qkvf [T,1536] -> qbh [HQ][T][64], kbh [HKV][T][64] fp32 -------
__global__ __launch_bounds__(256) void k_rope_cvt(const float* __restrict__ qkvf,
                                                  float* __restrict__ qbh,
                                                  float* __restrict__ kbh) {
  int t = blockIdx.x;
  const float* row = qkvf + (size_t)t * 1536;
  for (int it = threadIdx.x; it < (HQn + HKVn) * 32; it += 256) {
    int hh = it >> 5, i = it & 31;
    float inv = powf(10000.0f, -(float)i / 32.0f);
    float ang = (float)t * inv;
    float c = cosf(ang), s = sinf(ang);
    const float* p;
    float* dst;
    if (hh < HQn) {
      p = row + hh * 64;
      dst = qbh + ((size_t)hh * T_LEN + t) * 64;
    } else {
      int h2 = hh - HQn;
      p = row + 1024 + h2 * 64;
      dst = kbh + ((size_t)h2 * T_LEN + t) * 64;
    }
    float a = p[i], b = p[i + 32];
    dst[i] = a * c - b * s;
    dst[i + 32] = b * c + a * s;
  }
}

// ---------------- V transpose fp32: qkvf v-part -> vbt [HKV*64][T] ----------------
__global__ __launch_bounds__(256) void k_vT(const float* __restrict__ qkvf,
                                            float* __restrict__ vbt) {
  __shared__ float tile[32][33];
  int t0 = blockIdx.x * 32;
  int dh = blockIdx.y;
  int col0 = 1280 + dh * 32;
  int tc = threadIdx.x & 31, tr = threadIdx.x >> 5;
#pragma unroll
  for (int i = 0; i < 4; i++)
    tile[tr + i * 8][tc] = qkvf[(size_t)(t0 + tr + i * 8) * 1536 + col0 + tc];
  __syncthreads();
#pragma unroll
  for (int i = 0; i < 4; i++) {
    int dd = tr + i * 8;
    vbt[(size_t)(dh * 32 + dd) * T_LEN + t0 + tc] = tile[tc][dd];
  }
}

// ------- split-bf16 MFMA flash attention: 64 q-rows/block, fp32-accurate -------
// epilogue writes ob hi/lo bf16 split for the WO sgemm
__global__ __launch_bounds__(256) void k_attn(const float* __restrict__ qbh,
                                              const float* __restrict__ kbh,
                                              const float* __restrict__ vbt,
                                              ushort* __restrict__ obh,
                                              ushort* __restrict__ obl) {
  __shared__ ushort Kh[64][72], Kl[64][72], Vh[64][72], Vl[64][72];
  __shared__ ushort Psh[4][16][72], Psl[4][16][72];
  int qh = blockIdx.y, kvh = qh >> 2;
  int r0 = blockIdx.x * 64;
  int tid = threadIdx.x, wave = tid >> 6, lane = tid & 63;
  int quad = lane >> 4, l15 = lane & 15;
#pragma unroll
  for (int it = 0; it < 2; it++) {
    int c = tid + it * 256;
    int row = c >> 3, col = (c & 7) * 8;
    float va[8];
    short8 h8, l8;
    const float* src = qbh + ((size_t)qh * T_LEN + r0 + row) * 64 + col;
    *(float4*)(va) = *(const float4*)(src);
    *(float4*)(va + 4) = *(const float4*)(src + 4);
    split8(va, h8, l8);
    *(short8*)&Kh[row][col] = h8;
    *(short8*)&Kl[row][col] = l8;
  }
  __syncthreads();
  short8 aqh0 = *(short8*)&Kh[wave * 16 + l15][quad * 8];
  short8 aqh1 = *(short8*)&Kh[wave * 16 + l15][32 + quad * 8];
  short8 aql0 = *(short8*)&Kl[wave * 16 + l15][quad * 8];
  short8 aql1 = *(short8*)&Kl[wave * 16 + l15][32 + quad * 8];
  floatx4 oacc[4];
#pragma unroll
  for (int nt = 0; nt < 4; nt++) oacc[nt] = (floatx4){0.f, 0.f, 0.f, 0.f};
  float mrun[4], lrun[4];
#pragma unroll
  for (int r = 0; r < 4; r++) { mrun[r] = -INFINITY; lrun[r] = 0.f; }
  int cq = r0 >> 6;
  for (int cc = 0; cc <= cq; cc++) {
    __syncthreads();
#pragma unroll
    for (int it = 0; it < 2; it++) {
      int c = tid + it * 256;
      int row = c >> 3, col = (c & 7) * 8;
      float va[8];
      short8 h8, l8;
      const float* ks = kbh + ((size_t)kvh * T_LEN + cc * 64 + row) * 64 + col;
      *(float4*)(va) = *(const float4*)(ks);
      *(float4*)(va + 4) = *(const float4*)(ks + 4);
      split8(va, h8, l8);
      *(short8*)&Kh[row][col] = h8;
      *(short8*)&Kl[row][col] = l8;
      const float* vs = vbt + ((size_t)(kvh * 64 + row)) * T_LEN + cc * 64 + col;
      *(float4*)(va) = *(const float4*)(vs);
      *(float4*)(va + 4) = *(const float4*)(vs + 4);
      split8(va, h8, l8);
      *(short8*)&Vh[row][col] = h8;
      *(short8*)&Vl[row][col] = l8;
    }
    __syncthreads();
    floatx4 s[4];
#pragma unroll
    for (int nt = 0; nt < 4; nt++) {
      short8 bh0 = *(short8*)&Kh[nt * 16 + l15][quad * 8];
      short8 bh1 = *(short8*)&Kh[nt * 16 + l15][32 + quad * 8];
      short8 bl0 = *(short8*)&Kl[nt * 16 + l15][quad * 8];
      short8 bl1 = *(short8*)&Kl[nt * 16 + l15][32 + quad * 8];
      floatx4 z = (floatx4){0.f, 0.f, 0.f, 0.f};
      z = mfma16(aqh0, bh0, z);
      z = mfma16(aqh1, bh1, z);
      z = mfma16(aqh0, bl0, z);
      z = mfma16(aqh1, bl1, z);
      z = mfma16(aql0, bh0, z);
      z = mfma16(aql1, bh1, z);
      s[nt] = z;
    }
    int rowg0 = r0 + wave * 16 + quad * 4;
#pragma unroll
    for (int nt = 0; nt < 4; nt++) {
      int colg = cc * 64 + nt * 16 + l15;
#pragma unroll
      for (int r = 0; r < 4; r++) {
        float v = s[nt][r] * ATT_SCALE;
        s[nt][r] = (colg > rowg0 + r) ? -INFINITY : v;
      }
    }
    float mnew[4], alpha[4], psum[4];
#pragma unroll
    for (int r = 0; r < 4; r++) {
      float mx = fmaxf(fmaxf(s[0][r], s[1][r]), fmaxf(s[2][r], s[3][r]));
#pragma unroll
      for (int off = 1; off < 16; off <<= 1) mx = fmaxf(mx, __shfl_xor(mx, off, 64));
      mnew[r] = fmaxf(mrun[r], mx);
      psum[r] = 0.f;
    }
#pragma unroll
    for (int nt = 0; nt < 4; nt++)
#pragma unroll
      for (int r = 0; r < 4; r++) {
        float p = __expf(s[nt][r] - mnew[r]);
        s[nt][r] = p;
        psum[r] += p;
      }
#pragma unroll
    for (int r = 0; r < 4; r++) {
      float ps = psum[r];
#pragma unroll
      for (int off = 1; off < 16; off <<= 1) ps += __shfl_xor(ps, off, 64);
      alpha[r] = __expf(mrun[r] - mnew[r]);
      lrun[r] = lrun[r] * alpha[r] + ps;
      mrun[r] = mnew[r];
    }
#pragma unroll
    for (int nt = 0; nt < 4; nt++)
#pragma unroll
      for (int r = 0; r < 4; r++) oacc[nt][r] *= alpha[r];
#pragma unroll
    for (int nt = 0; nt < 4; nt++)
#pragma unroll
      for (int r = 0; r < 4; r++) {
        float p = s[nt][r];
        ushort ph = f2bf(p);
        Psh[wave][quad * 4 + r][nt * 16 + l15] = ph;
        Psl[wave][quad * 4 + r][nt * 16 + l15] = f2bf(p - bf2f(ph));
      }
    short8 aph0 = *(short8*)&Psh[wave][l15][quad * 8];
    short8 aph1 = *(short8*)&Psh[wave][l15][32 + quad * 8];
    short8 apl0 = *(short8*)&Psl[wave][l15][quad * 8];
    short8 apl1 = *(short8*)&Psl[wave][l15][32 + quad * 8];
#pragma unroll
    for (int nt = 0; nt < 4; nt++) {
      short8 bvh0 = *(short8*)&Vh[nt * 16 + l15][quad * 8];
      short8 bvh1 = *(short8*)&Vh[nt * 16 + l15][32 + quad * 8];
      short8 bvl0 = *(short8*)&Vl[nt * 16 + l15][quad * 8];
      short8 bvl1 = *(short8*)&Vl[nt * 16 + l15][32 + quad * 8];
      oacc[nt] = mfma16(aph0, bvh0, oacc[nt]);
      oacc[nt] = mfma16(aph1, bvh1, oacc[nt]);
      oacc[nt] = mfma16(aph0, bvl0, oacc[nt]);
      oacc[nt] = mfma16(aph1, bvl1, oacc[nt]);
      oacc[nt] = mfma16(apl0, bvh0, oacc[nt]);
      oacc[nt] = mfma16(apl1, bvh1, oacc[nt]);
    }
  }
#pragma unroll
  for (int nt = 0; nt < 4; nt++)
#pragma unroll
    for (int r = 0; r < 4; r++) {
      int rowg = r0 + wave * 16 + quad * 4 + r;
      float v = oacc[nt][r] / lrun[r];
      ushort h = f2bf(v);
      size_t idx = (size_t)rowg * D_DIM + qh * 64 + nt * 16 + l15;
      obh[idx] = h;
      obl[idx] = f2bf(v - bf2f(h));
    }
}

// ------- gate: exact fp32 rmsnorm + logits, top-2 picked on raw logits -------
__global__ __launch_bounds__(256) void k_gate(const float* __restrict__ x1,
                                              const float* __restrict__ g2,
                                              const float* __restrict__ gw,
                                              int* __restrict__ counts,
                                              int* __restrict__ ids,
                                              float* __restrict__ wts,
                                              float* __restrict__ load_sum) {
  int wave = threadIdx.x >> 6, lane = threadIdx.x & 63;
  int token = blockIdx.x * 4 + wave;
  const float* xp = x1 + (size_t)token * D_DIM;
  float acc[NE] = {};
  float ss = 0.f;
  for (int d = lane; d < D_DIM; d += 64) {
    float xv = xp[d];
    ss += xv * xv;
    float hv = xv * g2[d];
#pragma unroll
    for (int e = 0; e < NE; e++) acc[e] += hv * gw[d * NE + e];
  }
#pragma unroll
  for (int off = 32; off; off >>= 1) ss += __shfl_xor(ss, off, 64);
#pragma unroll
  for (int e = 0; e < NE; e++)
#pragma unroll
    for (int off = 32; off; off >>= 1) acc[e] += __shfl_xor(acc[e], off, 64);
  if (lane == 0) {
    float sc = rsqrtf(ss * (1.0f / D_DIM) + 1e-6f);
    float mx = -1e30f;
#pragma unroll
    for (int e = 0; e < NE; e++) { acc[e] *= sc; mx = fmaxf(mx, acc[e]); }
    float p[NE], sum = 0.f;
#pragma unroll
    for (int e = 0; e < NE; e++) { p[e] = expf(acc[e] - mx); sum += p[e]; }
#pragma unroll
    for (int e = 0; e < NE; e++) p[e] /= sum;
    int i1 = 0;
#pragma unroll
    for (int e = 1; e < NE; e++) if (acc[e] > acc[i1]) i1 = e;
    int i2 = (i1 == 0) ? 1 : 0;
#pragma unroll
    for (int e = 0; e < NE; e++) if (e != i1 && acc[e] > acc[i2]) i2 = e;
    float denom = p[i1] + p[i2] + 1e-8f;
    int pos = atomicAdd(&counts[i1], 1);
    ids[i1 * NTOK + pos] = token;
    wts[i1 * NTOK + pos] = p[i1] / denom;
    pos = atomicAdd(&counts[i2], 1);
    ids[i2 * NTOK + pos] = token;
    wts[i2 * NTOK + pos] = p[i2] / denom;
#pragma unroll
    for (int e = 0; e < NE; e++) atomicAdd(&load_sum[e], p[e]);
  }
}

__global__ void k_offsets(const int* __restrict__ counts, int* __restrict__ offsets) {
  if (threadIdx.x == 0 && blockIdx.x == 0) {
    int s = 0;
    for (int e = 0; e < NE; e++) { offsets[e] = s; s += counts[e]; }
  }
}

// ------- MoE gate/up bf16 MFMA GEMM (DMA-staged) + SiLU*up*w -> act bf16 -------
__global__ __launch_bounds__(256) void k_moe_gateup(const ushort* __restrict__ h,
                                                    const ushort* __restrict__ wgT,
                                                    const ushort* __restrict__ wuT,
                                                    const int* __restrict__ ids,
                                                    const float* __restrict__ wts,
                                                    const int* __restrict__ counts,
                                                    const int* __restrict__ offsets,
                                                    ushort* __restrict__ act) {
  int e = blockIdx.z;
  int cnt = counts[e];
  int m0 = blockIdx.y * 128;
  if (m0 >= cnt) return;
  int n0 = blockIdx.x * 128;
  __shared__ __align__(16) ushort As[4096], Bg[4096], Bu[4096];
  __shared__ int toks[128];
  __shared__ float wrow[128];
  int tid = threadIdx.x;
  if (tid < 128) {
    int mm = m0 + tid;
    toks[tid] = (mm < cnt) ? ids[e * NTOK + mm] : 0;
    wrow[tid] = (mm < cnt) ? wts[e * NTOK + mm] : 0.f;
  }
  __syncthreads();
  int wave = tid >> 6, lane = tid & 63, quad = lane >> 4, l15 = lane & 15;
  int wm = (wave >> 1) * 64, wn = (wave & 1) * 64;
  const ushort* Wg = wgT + (size_t)e * FF * D_DIM;
  const ushort* Wu = wuT + (size_t)e * FF * D_DIM;
  const ushort *sA[2], *sBg[2], *sBu[2];
  int dof[2];
#pragma unroll
  for (int j = 0; j < 2; j++) {
    int u = (wave * 2 + j) * 64 + lane;
    int chunk = u >> 7, row = u & 127;
    sA[j] = h + (size_t)toks[row] * D_DIM + chunk * 8;
    sBg[j] = Wg + (size_t)(n0 + row) * D_DIM + chunk * 8;  // OOB rows land in next ws buffer (mapped)
    sBu[j] = Wu + (size_t)(n0 + row) * D_DIM + chunk * 8;
    dof[j] = (wave * 2 + j) * 512;
  }
  floatx4 accg[4][4], accu[4][4];
#pragma unroll
  for (int i = 0; i < 4; i++)
#pragma unroll
    for (int j = 0; j < 4; j++) {
      accg[i][j] = (floatx4){0.f, 0.f, 0.f, 0.f};
      accu[i][j] = (floatx4){0.f, 0.f, 0.f, 0.f};
    }
  for (int k0 = 0; k0 < D_DIM; k0 += 32) {
#pragma unroll
    for (int j = 0; j < 2; j++) {
      DMA16(sA[j] + k0, As + dof[j]);
      DMA16(sBg[j] + k0, Bg + dof[j]);
      DMA16(sBu[j] + k0, Bu + dof[j]);
    }
    __syncthreads();
    short8 aF[4], gF[4], uF[4];
#pragma unroll
    for (int mt = 0; mt < 4; mt++) aF[mt] = *(short8*)&As[quad * 1024 + (wm + mt * 16 + l15) * 8];
#pragma unroll
    for (int nt = 0; nt < 4; nt++) {
      gF[nt] = *(short8*)&Bg[quad * 1024 + (wn + nt * 16 + l15) * 8];
      uF[nt] = *(short8*)&Bu[quad * 1024 + (wn + nt * 16 + l15) * 8];
    }
#pragma unroll
    for (int mt = 0; mt < 4; mt++)
#pragma unroll
      for (int nt = 0; nt < 4; nt++) {
        accg[mt][nt] = mfma16(aF[mt], gF[nt], accg[mt][nt]);
        accu[mt][nt] = mfma16(aF[mt], uF[nt], accu[mt][nt]);
      }
    __syncthreads();
  }
  int aoff = offsets[e];
#pragma unroll
  for (int mt = 0; mt < 4; mt++) {
    int mrow = wm + mt * 16 + quad * 4;
#pragma unroll
    for (int nt = 0; nt < 4; nt++) {
      int col = n0 + wn + nt * 16 + l15;
      if (col < FF) {
#pragma unroll
        for (int r = 0; r < 4; r++) {
          int ml = mrow + r;
          if (m0 + ml < cnt) {
            float g = accg[mt][nt][r];
            float u = accu[mt][nt][r];
            float sil = g / (1.f + __expf(-g));
            act[(size_t)(aoff + m0 + ml) * FF + col] = f2bf(sil * u * wrow[ml]);
          }
        }
      }
    }
  }
}

// ---------------- MoE down bf16 MFMA GEMM (DMA-staged), scatter-add ----------------
__global__ __launch_bounds__(256) void k_moe_down(const ushort* __restrict__ act,
                                                  const ushort* __restrict__ wdT,
                                                  const int* __restrict__ ids,
                                                  const int* __restrict__ counts,
                                                  const int* __restrict__ offsets,
                                                  float* __restrict__ moe_acc) {
  int e = blockIdx.z;
  int cnt = counts[e];
  int m0 = blockIdx.y * 128;
  if (m0 >= cnt) return;
  int n0 = blockIdx.x * 128;
  __shared__ __align__(16) ushort As[4096], Bs[4096];
  __shared__ int toks[128];
  int tid = threadIdx.x;
  if (tid < 128) {
    int mm = m0 + tid;
    toks[tid] = (mm < cnt) ? ids[e * NTOK + mm] : 0;
  }
  __syncthreads();
  int wave = tid >> 6, lane = tid & 63, quad = lane >> 4, l15 = lane & 15;
  int wm = (wave >> 1) * 64, wn = (wave & 1) * 64;
  int aoff = offsets[e];
  const ushort* Wd = wdT + (size_t)e * D_DIM * FF;
  const ushort *sA[2], *sB[2];
  int dof[2];
#pragma unroll
  for (int j = 0; j < 2; j++) {
    int u = (wave * 2 + j) * 64 + lane;
    int chunk = u >> 7, row = u & 127;
    sA[j] = act + (size_t)(aoff + m0 + row) * FF + chunk * 8;
    sB[j] = Wd + (size_t)(n0 + row) * FF + chunk * 8;
    dof[j] = (wave * 2 + j) * 512;
  }
  floatx4 acc[4][4];
#pragma unroll
  for (int i = 0; i < 4; i++)
#pragma unroll
    for (int j = 0; j < 4; j++) acc[i][j] = (floatx4){0.f, 0.f, 0.f, 0.f};
  for (int k0 = 0; k0 < FF; k0 += 32) {
#pragma unroll
    for (int j = 0; j < 2; j++) {
      DMA16(sA[j] + k0, As + dof[j]);
      DMA16(sB[j] + k0, Bs + dof[j]);
    }
    __syncthreads();
    short8 aF[4], bF[4];
#pragma unroll
    for (int mt = 0; mt < 4; mt++) aF[mt] = *(short8*)&As[quad * 1024 + (wm + mt * 16 + l15) * 8];
#pragma unroll
    for (int nt = 0; nt < 4; nt++) bF[nt] = *(short8*)&Bs[quad * 1024 + (wn + nt * 16 + l15) * 8];
#pragma unroll
    for (int mt = 0; mt < 4; mt++)
#pragma unroll
      for (int nt = 0; nt < 4; nt++) acc[mt][nt] = mfma16(aF[mt], bF[nt], acc[mt][nt]);
    __syncthreads();
  }
#pragma unroll
  for (int mt = 0; mt < 4; mt++) {
    int mrow = wm + mt * 16 + quad * 4;
#pragma unroll
    for (int nt = 0; nt < 4; nt++) {
      int col = n0 + wn + nt * 16 + l15;
#pragma unroll
      for (int r = 0; r < 4; r++) {
        int ml = mrow + r;
        if (m0 + ml < cnt)
          atomicAdd(&moe_acc[(size_t)toks[ml] * D_DIM + col], acc[mt][nt][r]);
      }
    }
  }
}

__global__ __launch_bounds__(256) void k_add(const float* __restrict__ a,
                                             const float* __restrict__ b,
                                             float* __restrict__ o) {
  int i = blockIdx.x * 256 + threadIdx.x;
  float4 va = ((const float4*)a)[i];
  float4 vb = ((const float4*)b)[i];
  float4 vo;
  vo.x = va.x + vb.x; vo.y = va.y + vb.y; vo.z = va.z + vb.z; vo.w = va.w + vb.w;
  ((float4*)o)[i] = vo;
}

__global__ void k_aux(const int* __restrict__ counts, const float* __restrict__ load_sum,
                      float* __restrict__ out_aux) {
  if (threadIdx.x == 0 && blockIdx.x == 0) {
    float s = 0.f;
    for (int e = 0; e < NE; e++)
      s += ((float)counts[e] / (float)NSLOT) * (load_sum[e] / (float)NTOK);
    *out_aux = 0.01f * (float)NE * s;
  }
}

extern "C" void kernel_launch(void* const* d_in, const int* in_sizes, int n_in,
                              void* d_out, int out_size, void* d_ws, size_t ws_size,
                              hipStream_t stream) {
  const float* x = (const float*)d_in[0];
  const float* g1 = (const float*)d_in[1];
  const float* g2 = (const float*)d_in[2];
  const float* wq = (const float*)d_in[3];
  const float* wk = (const float*)d_in[4];
  const float* wv = (const float*)d_in[5];
  const float* wo = (const float*)d_in[6];
  const float* gate_w = (const float*)d_in[7];
  const float* we_gate = (const float*)d_in[8];
  const float* we_up = (const float*)d_in[9];
  const float* we_down = (const float*)d_in[10];
  float* out = (float*)d_out;

  char* w = (char*)d_ws;
  size_t o = 0;
  auto alloc = [&](size_t bytes) -> char* {
    char* p = w + o;
    o = (o + bytes + 255) & ~(size_t)255;
    return p;
  };
  ushort* h1h = (ushort*)alloc((size_t)NTOK * D_DIM * 2);
  ushort* h1l = (ushort*)alloc((size_t)NTOK * D_DIM * 2);
  float* qkvf = (float*)alloc((size_t)NTOK * 1536 * 4);
  float* qbh = (float*)alloc((size_t)HQn * T_LEN * 64 * 4);
  float* kbh = (float*)alloc((size_t)HKVn * T_LEN * 64 * 4);
  float* vbt = (float*)alloc((size_t)HKVn * 64 * T_LEN * 4);
  ushort* obh = (ushort*)alloc((size_t)NTOK * D_DIM * 2);
  ushort* obl = (ushort*)alloc((size_t)NTOK * D_DIM * 2);
  float* x1 = (float*)alloc((size_t)NTOK * D_DIM * 4);
  float* moe_acc = (float*)alloc((size_t)NTOK * D_DIM * 4);
  ushort* act = (ushort*)alloc((size_t)(NSLOT + 128) * FF * 2);
  ushort* qkvwTh = (ushort*)alloc((size_t)1536 * 1024 * 2);
  ushort* qkvwTl = (ushort*)alloc((size_t)1536 * 1024 * 2);
  ushort* woTh = (ushort*)alloc((size_t)1024 * 1024 * 2);
  ushort* woTl = (ushort*)alloc((size_t)1024 * 1024 * 2);
  ushort* h2h = (ushort*)alloc((size_t)NTOK * D_DIM * 2);
  ushort* h2l = (ushort*)alloc((size_t)NTOK * D_DIM * 2);
  ushort* wgT = (ushort*)alloc((size_t)NE * FF * D_DIM * 2);
  ushort* wuT = (ushort*)alloc((size_t)NE * FF * D_DIM * 2);
  ushort* wdT = (ushort*)alloc((size_t)NE * D_DIM * FF * 2);
  int* counts = (int*)alloc(NE * 4);
  int* offsets = (int*)alloc(NE * 4);
  float* load_sum = (float*)alloc(NE * 4);
  int* ids = (int*)alloc((size_t)NE * NTOK * 4);
  float* wts = (float*)alloc((size_t)NE * NTOK * 4);

  hipMemsetAsync(moe_acc, 0, (size_t)NTOK * D_DIM * 4, stream);
  hipMemsetAsync(counts, 0, 768, stream);  // counts+offsets+load_sum slots

  // weight transposes (hi/lo split for fp32-accurate attention path, bf16 for experts)
  k_cvtT2<<<dim3(32, 32), 256, 0, stream>>>(wq, qkvwTh, qkvwTl, 1024, 1024);
  k_cvtT2<<<dim3(8, 32), 256, 0, stream>>>(wk, qkvwTh + (size_t)1024 * 1024,
                                           qkvwTl + (size_t)1024 * 1024, 1024, 256);
  k_cvtT2<<<dim3(8, 32), 256, 0, stream>>>(wv, qkvwTh + (size_t)1280 * 1024,
                                           qkvwTl + (size_t)1280 * 1024, 1024, 256);
  k_cvtT2<<<dim3(32, 32), 256, 0, stream>>>(wo, woTh, woTl, 1024, 1024);
  k_cvtT<<<dim3(86, 32, 8), 256, 0, stream>>>(we_gate, wgT, 1024, 2752);
  k_cvtT<<<dim3(86, 32, 8), 256, 0, stream>>>(we_up, wuT, 1024, 2752);
  k_cvtT<<<dim3(32, 86, 8), 256, 0, stream>>>(we_down, wdT, 2752, 1024);

  // attention path (fp32-accurate via split-bf16 MFMA)
  k_rmsnorm2<<<NTOK, 256, 0, stream>>>(x, g1, h1h, h1l);
  k_sgemm<<<dim3(12, 16), 256, 0, stream>>>(h1h, h1l, qkvwTh, qkvwTl, qkvf, nullptr,
                                            1536, 1024);
  k_rope_cvt<<<T_LEN, 256, 0, stream>>>(qkvf, qbh, kbh);
  k_vT<<<dim3(64, 8), 256, 0, stream>>>(qkvf, vbt);
  k_attn<<<dim3(32, 16), 256, 0, stream>>>(qbh, kbh, vbt, obh, obl);
  k_sgemm<<<dim3(8, 16), 256, 0, stream>>>(obh, obl, woTh, woTl, x1, x, 1024, 1024);

  // moe
  k_rmsnorm2<<<NTOK, 256, 0, stream>>>(x1, g2, h2h, h2l);
  k_gate<<<NTOK / 4, 256, 0, stream>>>(x1, g2, gate_w, counts, ids, wts, load_sum);
  k_offsets<<<1, 1, 0, stream>>>(counts, offsets);
  k_moe_gateup<<<dim3(22, 16, 8), 256, 0, stream>>>(h2h, wgT, wuT, ids, wts, counts,
                                                    offsets, act);
  k_moe_down<<<dim3(8, 16, 8), 256, 0, stream>>>(act, wdT, ids, counts, offsets, moe_acc);
  k_add<<<(NTOK * D_DIM) / (256 * 4), 256, 0, stream>>>(x1, moe_acc, out);
  k_aux<<<1, 1, 0, stream>>>(counts, load_sum, out + (size_t)NTOK * D_DIM);
}

// Round 5
// 961.589 us; speedup vs baseline: 3.9496x; 1.2085x over previous
//
#include <hip/hip_runtime.h>
#include <cstdint>

typedef __attribute__((ext_vector_type(8))) short short8;
typedef __attribute__((ext_vector_type(4))) float floatx4;
typedef __attribute__((ext_vector_type(4))) unsigned short ushort4v;
typedef unsigned short ushort;

#define T_LEN 2048
#define D_DIM 1024
#define HQn 16
#define HKVn 4
#define NE 8
#define FF 2752
#define NTOK 2048
#define NSLOT 4096
#define ATT_SCALE 0.125f
#define GATE_TPB 16

__device__ inline ushort f2bf(float f) {
  union { float f; unsigned int i; } v; v.f = f;
  unsigned int r = v.i + 0x7fffu + ((v.i >> 16) & 1u);
  return (ushort)(r >> 16);
}
__device__ inline float bf2f(ushort h) {
  union { unsigned int i; float f; } v; v.i = ((unsigned int)h) << 16;
  return v.f;
}
__device__ inline void split8(const float* v, short8& hi, short8& lo) {
#pragma unroll
  for (int i = 0; i < 8; i++) {
    ushort h = f2bf(v[i]);
    hi[i] = (short)h;
    lo[i] = (short)f2bf(v[i] - bf2f(h));
  }
}
__device__ inline floatx4 mfma16(short8 a, short8 b, floatx4 c) {
  return __builtin_amdgcn_mfma_f32_16x16x32_bf16(a, b, c, 0, 0, 0);
}
// async global->LDS, 16B per lane; LDS dest = wave-uniform base + lane*16
#define DMA16(g, l)                                                              \
  __builtin_amdgcn_global_load_lds((const __attribute__((address_space(1))) void*)(g), \
                                   (__attribute__((address_space(3))) void*)(l), 16, 0, 0)

// ---------------- transpose+convert fp32 -> bf16 [C][R] (batch z) ----------------
__global__ __launch_bounds__(256) void k_cvtT(const float* __restrict__ src,
                                              ushort* __restrict__ dst, int R, int C) {
  __shared__ float tile[32][33];
  size_t sb = (size_t)blockIdx.z * R * C;
  const float* s = src + sb;
  ushort* d = dst + sb;
  int r0 = blockIdx.y * 32, c0 = blockIdx.x * 32;
  int tc = threadIdx.x & 31, tr = threadIdx.x >> 5;
#pragma unroll
  for (int i = 0; i < 4; i++)
    tile[tr + i * 8][tc] = s[(size_t)(r0 + tr + i * 8) * C + c0 + tc];
  __syncthreads();
#pragma unroll
  for (int i = 0; i < 4; i++) {
    int cc = tr + i * 8;
    d[(size_t)(c0 + cc) * R + r0 + tc] = f2bf(tile[tc][cc]);
  }
}

// ---------------- transpose+split fp32 -> hi/lo bf16 [C][R] ----------------
__global__ __launch_bounds__(256) void k_cvtT2(const float* __restrict__ src,
                                               ushort* __restrict__ dh,
                                               ushort* __restrict__ dl, int R, int C) {
  __shared__ float tile[32][33];
  int r0 = blockIdx.y * 32, c0 = blockIdx.x * 32;
  int tc = threadIdx.x & 31, tr = threadIdx.x >> 5;
#pragma unroll
  for (int i = 0; i < 4; i++)
    tile[tr + i * 8][tc] = src[(size_t)(r0 + tr + i * 8) * C + c0 + tc];
  __syncthreads();
#pragma unroll
  for (int i = 0; i < 4; i++) {
    int cc = tr + i * 8;
    float v = tile[tc][cc];
    ushort h = f2bf(v);
    dh[(size_t)(c0 + cc) * R + r0 + tc] = h;
    dl[(size_t)(c0 + cc) * R + r0 + tc] = f2bf(v - bf2f(h));
  }
}

// ---------------- RMSNorm fp32 -> hi/lo bf16 split ----------------
__global__ __launch_bounds__(256) void k_rmsnorm2(const float* __restrict__ x,
                                                  const float* __restrict__ g,
                                                  ushort* __restrict__ oh,
                                                  ushort* __restrict__ ol) {
  int row = blockIdx.x;
  int t = threadIdx.x;
  const float4* x4 = (const float4*)(x + (size_t)row * D_DIM);
  float4 v = x4[t];
  float ss = v.x * v.x + v.y * v.y + v.z * v.z + v.w * v.w;
#pragma unroll
  for (int off = 32; off; off >>= 1) ss += __shfl_xor(ss, off, 64);
  __shared__ float red[4];
  if ((t & 63) == 0) red[t >> 6] = ss;
  __syncthreads();
  float tot = red[0] + red[1] + red[2] + red[3];
  float sc = rsqrtf(tot * (1.0f / D_DIM) + 1e-6f);
  const float4* g4 = (const float4*)g;
  float4 gv = g4[t];
  float vals[4] = {v.x * gv.x * sc, v.y * gv.y * sc, v.z * gv.z * sc, v.w * gv.w * sc};
  ushort4v h4, l4;
#pragma unroll
  for (int i = 0; i < 4; i++) {
    ushort h = f2bf(vals[i]);
    h4[i] = h;
    l4[i] = f2bf(vals[i] - bf2f(h));
  }
  *(ushort4v*)(oh + (size_t)row * D_DIM + t * 4) = h4;
  *(ushort4v*)(ol + (size_t)row * D_DIM + t * 4) = l4;
}

// ------- split-bf16 emulated-fp32 MFMA GEMM (DMA-staged): C = A @ Bt^T (+res) -------
__global__ __launch_bounds__(256) void k_sgemm(const ushort* __restrict__ Ahg,
                                               const ushort* __restrict__ Alg,
                                               const ushort* __restrict__ Bhg,
                                               const ushort* __restrict__ Blg,
                                               float* __restrict__ C,
                                               const float* __restrict__ res,
                                               int N, int K) {
  __shared__ __align__(16) ushort Ah[4096], Al[4096], Bh[4096], Bl[4096];
  int tid = threadIdx.x;
  int m0 = blockIdx.y * 128, n0 = blockIdx.x * 128;
  int wave = tid >> 6, lane = tid & 63, quad = lane >> 4, l15 = lane & 15;
  int wm = (wave >> 1) * 64, wn = (wave & 1) * 64;
  floatx4 acc[4][4];
#pragma unroll
  for (int i = 0; i < 4; i++)
#pragma unroll
    for (int j = 0; j < 4; j++) acc[i][j] = (floatx4){0.f, 0.f, 0.f, 0.f};
  const ushort *sAh[2], *sAl[2], *sBh[2], *sBl[2];
  int dof[2];
#pragma unroll
  for (int j = 0; j < 2; j++) {
    int u = (wave * 2 + j) * 64 + lane;
    int chunk = u >> 7, row = u & 127;
    sAh[j] = Ahg + (size_t)(m0 + row) * K + chunk * 8;
    sAl[j] = Alg + (size_t)(m0 + row) * K + chunk * 8;
    sBh[j] = Bhg + (size_t)(n0 + row) * K + chunk * 8;
    sBl[j] = Blg + (size_t)(n0 + row) * K + chunk * 8;
    dof[j] = (wave * 2 + j) * 512;
  }
  for (int k0 = 0; k0 < K; k0 += 32) {
#pragma unroll
    for (int j = 0; j < 2; j++) {
      DMA16(sAh[j] + k0, Ah + dof[j]);
      DMA16(sAl[j] + k0, Al + dof[j]);
      DMA16(sBh[j] + k0, Bh + dof[j]);
      DMA16(sBl[j] + k0, Bl + dof[j]);
    }
    __syncthreads();
    short8 ah[4], al[4], bh[4], bl[4];
#pragma unroll
    for (int mt = 0; mt < 4; mt++) {
      int ar = wm + mt * 16 + l15;
      ah[mt] = *(short8*)&Ah[quad * 1024 + ar * 8];
      al[mt] = *(short8*)&Al[quad * 1024 + ar * 8];
    }
#pragma unroll
    for (int nt = 0; nt < 4; nt++) {
      int br = wn + nt * 16 + l15;
      bh[nt] = *(short8*)&Bh[quad * 1024 + br * 8];
      bl[nt] = *(short8*)&Bl[quad * 1024 + br * 8];
    }
#pragma unroll
    for (int mt = 0; mt < 4; mt++)
#pragma unroll
      for (int nt = 0; nt < 4; nt++) {
        acc[mt][nt] = mfma16(ah[mt], bh[nt], acc[mt][nt]);
        acc[mt][nt] = mfma16(ah[mt], bl[nt], acc[mt][nt]);
        acc[mt][nt] = mfma16(al[mt], bh[nt], acc[mt][nt]);
      }
    __syncthreads();
  }
#pragma unroll
  for (int mt = 0; mt < 4; mt++) {
    int row = m0 + wm + mt * 16 + quad * 4;
#pragma unroll
    for (int nt = 0; nt < 4; nt++) {
      int col = n0 + wn + nt * 16 + l15;
#pragma unroll
      for (int r = 0; r < 4; r++) {
        float v = acc[mt][nt][r];
        if (res) v += res[(size_t)(row + r) * N + col];
        C[(size_t)(row + r) * N + col] = v;
      }
    }
  }
}

// ------- RoPE fp32: qkvf [T,1536] -> qbh [HQ][T][64], kbh [HKV][T][64] fp32 -------
__global__ __launch_bounds__(256) void k_rope_cvt(const float* __restrict__ qkvf,
                                                  float* __restrict__ qbh,
                                                  float* __restrict__ kbh) {
  int t = blockIdx.x;
  const float* row = qkvf + (size_t)t * 1536;
  for (int it = threadIdx.x; it < (HQn + HKVn) * 32; it += 256) {
    int hh = it >> 5, i = it & 31;
    float inv = powf(10000.0f, -(float)i / 32.0f);
    float ang = (float)t * inv;
    float c = cosf(ang), s = sinf(ang);
    const float* p;
    float* dst;
    if (hh < HQn) {
      p = row + hh * 64;
      dst = qbh + ((size_t)hh * T_LEN + t) * 64;
    } else {
      int h2 = hh - HQn;
      p = row + 1024 + h2 * 64;
      dst = kbh + ((size_t)h2 * T_LEN + t) * 64;
    }
    float a = p[i], b = p[i + 32];
    dst[i] = a * c - b * s;
    dst[i + 32] = b * c + a * s;
  }
}

// ---------------- V transpose fp32: qkvf v-part -> vbt [HKV*64][T] ----------------
__global__ __launch_bounds__(256) void k_vT(const float* __restrict__ qkvf,
                                            float* __restrict__ vbt) {
  __shared__ float tile[32][33];
  int t0 = blockIdx.x * 32;
  int dh = blockIdx.y;
  int col0 = 1280 + dh * 32;
  int tc = threadIdx.x & 31, tr = threadIdx.x >> 5;
#pragma unroll
  for (int i = 0; i < 4; i++)
    tile[tr + i * 8][tc] = qkvf[(size_t)(t0 + tr + i * 8) * 1536 + col0 + tc];
  __syncthreads();
#pragma unroll
  for (int i = 0; i < 4; i++) {
    int dd = tr + i * 8;
    vbt[(size_t)(dh * 32 + dd) * T_LEN + t0 + tc] = tile[tc][dd];
  }
}

// ------- split-bf16 MFMA flash attention: 64 q-rows/block, fp32-accurate -------
__global__ __launch_bounds__(256) void k_attn(const float* __restrict__ qbh,
                                              const float* __restrict__ kbh,
                                              const float* __restrict__ vbt,
                                              ushort* __restrict__ obh,
                                              ushort* __restrict__ obl) {
  __shared__ ushort Kh[64][72], Kl[64][72], Vh[64][72], Vl[64][72];
  __shared__ ushort Psh[4][16][72], Psl[4][16][72];
  int qh = blockIdx.y, kvh = qh >> 2;
  int r0 = blockIdx.x * 64;
  int tid = threadIdx.x, wave = tid >> 6, lane = tid & 63;
  int quad = lane >> 4, l15 = lane & 15;
#pragma unroll
  for (int it = 0; it < 2; it++) {
    int c = tid + it * 256;
    int row = c >> 3, col = (c & 7) * 8;
    float va[8];
    short8 h8, l8;
    const float* src = qbh + ((size_t)qh * T_LEN + r0 + row) * 64 + col;
    *(float4*)(va) = *(const float4*)(src);
    *(float4*)(va + 4) = *(const float4*)(src + 4);
    split8(va, h8, l8);
    *(short8*)&Kh[row][col] = h8;
    *(short8*)&Kl[row][col] = l8;
  }
  __syncthreads();
  short8 aqh0 = *(short8*)&Kh[wave * 16 + l15][quad * 8];
  short8 aqh1 = *(short8*)&Kh[wave * 16 + l15][32 + quad * 8];
  short8 aql0 = *(short8*)&Kl[wave * 16 + l15][quad * 8];
  short8 aql1 = *(short8*)&Kl[wave * 16 + l15][32 + quad * 8];
  floatx4 oacc[4];
#pragma unroll
  for (int nt = 0; nt < 4; nt++) oacc[nt] = (floatx4){0.f, 0.f, 0.f, 0.f};
  float mrun[4], lrun[4];
#pragma unroll
  for (int r = 0; r < 4; r++) { mrun[r] = -INFINITY; lrun[r] = 0.f; }
  int cq = r0 >> 6;
  for (int cc = 0; cc <= cq; cc++) {
    __syncthreads();
#pragma unroll
    for (int it = 0; it < 2; it++) {
      int c = tid + it * 256;
      int row = c >> 3, col = (c & 7) * 8;
      float va[8];
      short8 h8, l8;
      const float* ks = kbh + ((size_t)kvh * T_LEN + cc * 64 + row) * 64 + col;
      *(float4*)(va) = *(const float4*)(ks);
      *(float4*)(va + 4) = *(const float4*)(ks + 4);
      split8(va, h8, l8);
      *(short8*)&Kh[row][col] = h8;
      *(short8*)&Kl[row][col] = l8;
      const float* vs = vbt + ((size_t)(kvh * 64 + row)) * T_LEN + cc * 64 + col;
      *(float4*)(va) = *(const float4*)(vs);
      *(float4*)(va + 4) = *(const float4*)(vs + 4);
      split8(va, h8, l8);
      *(short8*)&Vh[row][col] = h8;
      *(short8*)&Vl[row][col] = l8;
    }
    __syncthreads();
    floatx4 s[4];
#pragma unroll
    for (int nt = 0; nt < 4; nt++) {
      short8 bh0 = *(short8*)&Kh[nt * 16 + l15][quad * 8];
      short8 bh1 = *(short8*)&Kh[nt * 16 + l15][32 + quad * 8];
      short8 bl0 = *(short8*)&Kl[nt * 16 + l15][quad * 8];
      short8 bl1 = *(short8*)&Kl[nt * 16 + l15][32 + quad * 8];
      floatx4 z = (floatx4){0.f, 0.f, 0.f, 0.f};
      z = mfma16(aqh0, bh0, z);
      z = mfma16(aqh1, bh1, z);
      z = mfma16(aqh0, bl0, z);
      z = mfma16(aqh1, bl1, z);
      z = mfma16(aql0, bh0, z);
      z = mfma16(aql1, bh1, z);
      s[nt] = z;
    }
    int rowg0 = r0 + wave * 16 + quad * 4;
#pragma unroll
    for (int nt = 0; nt < 4; nt++) {
      int colg = cc * 64 + nt * 16 + l15;
#pragma unroll
      for (int r = 0; r < 4; r++) {
        float v = s[nt][r] * ATT_SCALE;
        s[nt][r] = (colg > rowg0 + r) ? -INFINITY : v;
      }
    }
    float mnew[4], alpha[4], psum[4];
#pragma unroll
    for (int r = 0; r < 4; r++) {
      float mx = fmaxf(fmaxf(s[0][r], s[1][r]), fmaxf(s[2][r], s[3][r]));
#pragma unroll
      for (int off = 1; off < 16; off <<= 1) mx = fmaxf(mx, __shfl_xor(mx, off, 64));
      mnew[r] = fmaxf(mrun[r], mx);
      psum[r] = 0.f;
    }
#pragma unroll
    for (int nt = 0; nt < 4; nt++)
#pragma unroll
      for (int r = 0; r < 4; r++) {
        float p = __expf(s[nt][r] - mnew[r]);
        s[nt][r] = p;
        psum[r] += p;
      }
#pragma unroll
    for (int r = 0; r < 4; r++) {
      float ps = psum[r];
#pragma unroll
      for (int off = 1; off < 16; off <<= 1) ps += __shfl_xor(ps, off, 64);
      alpha[r] = __expf(mrun[r] - mnew[r]);
      lrun[r] = lrun[r] * alpha[r] + ps;
      mrun[r] = mnew[r];
    }
#pragma unroll
    for (int nt = 0; nt < 4; nt++)
#pragma unroll
      for (int r = 0; r < 4; r++) oacc[nt][r] *= alpha[r];
#pragma unroll
    for (int nt = 0; nt < 4; nt++)
#pragma unroll
      for (int r = 0; r < 4; r++) {
        float p = s[nt][r];
        ushort ph = f2bf(p);
        Psh[wave][quad * 4 + r][nt * 16 + l15] = ph;
        Psl[wave][quad * 4 + r][nt * 16 + l15] = f2bf(p - bf2f(ph));
      }
    short8 aph0 = *(short8*)&Psh[wave][l15][quad * 8];
    short8 aph1 = *(short8*)&Psh[wave][l15][32 + quad * 8];
    short8 apl0 = *(short8*)&Psl[wave][l15][quad * 8];
    short8 apl1 = *(short8*)&Psl[wave][l15][32 + quad * 8];
#pragma unroll
    for (int nt = 0; nt < 4; nt++) {
      short8 bvh0 = *(short8*)&Vh[nt * 16 + l15][quad * 8];
      short8 bvh1 = *(short8*)&Vh[nt * 16 + l15][32 + quad * 8];
      short8 bvl0 = *(short8*)&Vl[nt * 16 + l15][quad * 8];
      short8 bvl1 = *(short8*)&Vl[nt * 16 + l15][32 + quad * 8];
      oacc[nt] = mfma16(aph0, bvh0, oacc[nt]);
      oacc[nt] = mfma16(aph1, bvh1, oacc[nt]);
      oacc[nt] = mfma16(aph0, bvl0, oacc[nt]);
      oacc[nt] = mfma16(aph1, bvl1, oacc[nt]);
      oacc[nt] = mfma16(apl0, bvh0, oacc[nt]);
      oacc[nt] = mfma16(apl1, bvh1, oacc[nt]);
    }
  }
#pragma unroll
  for (int nt = 0; nt < 4; nt++)
#pragma unroll
    for (int r = 0; r < 4; r++) {
      int rowg = r0 + wave * 16 + quad * 4 + r;
      float v = oacc[nt][r] / lrun[r];
      ushort h = f2bf(v);
      size_t idx = (size_t)rowg * D_DIM + qh * 64 + nt * 16 + l15;
      obh[idx] = h;
      obl[idx] = f2bf(v - bf2f(h));
    }
}

// ------- gate: fp32 rmsnorm+logits, hierarchical routing (block-level atomics) -------
__global__ __launch_bounds__(256) void k_gate(const float* __restrict__ x1,
                                              const float* __restrict__ g2,
                                              const float* __restrict__ gw,
                                              int* __restrict__ counts,
                                              int* __restrict__ ids,
                                              float* __restrict__ wts,
                                              float* __restrict__ load_sum) {
  __shared__ float lsum[NE];
  __shared__ int lcount[NE];
  __shared__ int lbase[NE];
  __shared__ int ltok[GATE_TPB * 2];
  __shared__ int lexp[GATE_TPB * 2];
  __shared__ float lwt[GATE_TPB * 2];
  int tid = threadIdx.x, wave = tid >> 6, lane = tid & 63;
  if (tid < NE) { lsum[tid] = 0.f; lcount[tid] = 0; }
  __syncthreads();
  int t0 = blockIdx.x * GATE_TPB;
#pragma unroll
  for (int tt = 0; tt < GATE_TPB / 4; tt++) {
    int tloc = tt * 4 + wave;
    int token = t0 + tloc;
    const float* xp = x1 + (size_t)token * D_DIM;
    float acc[NE] = {};
    float ss = 0.f;
    for (int d = lane; d < D_DIM; d += 64) {
      float xv = xp[d];
      ss += xv * xv;
      float hv = xv * g2[d];
#pragma unroll
      for (int e = 0; e < NE; e++) acc[e] += hv * gw[d * NE + e];
    }
#pragma unroll
    for (int off = 32; off; off >>= 1) ss += __shfl_xor(ss, off, 64);
#pragma unroll
    for (int e = 0; e < NE; e++)
#pragma unroll
      for (int off = 32; off; off >>= 1) acc[e] += __shfl_xor(acc[e], off, 64);
    if (lane == 0) {
      float sc = rsqrtf(ss * (1.0f / D_DIM) + 1e-6f);
      float mx = -1e30f;
#pragma unroll
      for (int e = 0; e < NE; e++) { acc[e] *= sc; mx = fmaxf(mx, acc[e]); }
      float p[NE], sum = 0.f;
#pragma unroll
      for (int e = 0; e < NE; e++) { p[e] = expf(acc[e] - mx); sum += p[e]; }
#pragma unroll
      for (int e = 0; e < NE; e++) p[e] /= sum;
      int i1 = 0;
#pragma unroll
      for (int e = 1; e < NE; e++) if (acc[e] > acc[i1]) i1 = e;
      int i2 = (i1 == 0) ? 1 : 0;
#pragma unroll
      for (int e = 0; e < NE; e++) if (e != i1 && acc[e] > acc[i2]) i2 = e;
      float denom = p[i1] + p[i2] + 1e-8f;
      int slot = tloc * 2;
      lexp[slot] = i1; ltok[slot] = token; lwt[slot] = p[i1] / denom;
      lexp[slot + 1] = i2; ltok[slot + 1] = token; lwt[slot + 1] = p[i2] / denom;
      atomicAdd(&lcount[i1], 1);
      atomicAdd(&lcount[i2], 1);
#pragma unroll
      for (int e = 0; e < NE; e++) atomicAdd(&lsum[e], p[e]);
    }
  }
  __syncthreads();
  if (tid < NE) {
    lbase[tid] = atomicAdd(&counts[tid], lcount[tid]);
    atomicAdd(&load_sum[tid], lsum[tid]);
    lcount[tid] = 0;
  }
  __syncthreads();
  if (tid < GATE_TPB * 2) {
    int e = lexp[tid];
    int off = atomicAdd(&lcount[e], 1);
    int pos = lbase[e] + off;
    ids[e * NTOK + pos] = ltok[tid];
    wts[e * NTOK + pos] = lwt[tid];
  }
}

__global__ void k_offsets(const int* __restrict__ counts, int* __restrict__ offsets) {
  if (threadIdx.x == 0 && blockIdx.x == 0) {
    int s = 0;
    for (int e = 0; e < NE; e++) { offsets[e] = s; s += counts[e]; }
  }
}

// ------- MoE gate/up bf16 MFMA GEMM (DMA-staged) + SiLU*up*w -> act bf16 -------
__global__ __launch_bounds__(256) void k_moe_gateup(const ushort* __restrict__ h,
                                                    const ushort* __restrict__ wgT,
                                                    const ushort* __restrict__ wuT,
                                                    const int* __restrict__ ids,
                                                    const float* __restrict__ wts,
                                                    const int* __restrict__ counts,
                                                    const int* __restrict__ offsets,
                                                    ushort* __restrict__ act) {
  int e = blockIdx.z;
  int cnt = counts[e];
  int m0 = blockIdx.y * 128;
  if (m0 >= cnt) return;
  int n0 = blockIdx.x * 128;
  __shared__ __align__(16) ushort As[4096], Bg[4096], Bu[4096];
  __shared__ int toks[128];
  __shared__ float wrow[128];
  int tid = threadIdx.x;
  if (tid < 128) {
    int mm = m0 + tid;
    toks[tid] = (mm < cnt) ? ids[e * NTOK + mm] : 0;
    wrow[tid] = (mm < cnt) ? wts[e * NTOK + mm] : 0.f;
  }
  __syncthreads();
  int wave = tid >> 6, lane = tid & 63, quad = lane >> 4, l15 = lane & 15;
  int wm = (wave >> 1) * 64, wn = (wave & 1) * 64;
  const ushort* Wg = wgT + (size_t)e * FF * D_DIM;
  const ushort* Wu = wuT + (size_t)e * FF * D_DIM;
  const ushort *sA[2], *sBg[2], *sBu[2];
  int dof[2];
#pragma unroll
  for (int j = 0; j < 2; j++) {
    int u = (wave * 2 + j) * 64 + lane;
    int chunk = u >> 7, row = u & 127;
    sA[j] = h + (size_t)toks[row] * D_DIM + chunk * 8;
    sBg[j] = Wg + (size_t)(n0 + row) * D_DIM + chunk * 8;
    sBu[j] = Wu + (size_t)(n0 + row) * D_DIM + chunk * 8;
    dof[j] = (wave * 2 + j) * 512;
  }
  floatx4 accg[4][4], accu[4][4];
#pragma unroll
  for (int i = 0; i < 4; i++)
#pragma unroll
    for (int j = 0; j < 4; j++) {
      accg[i][j] = (floatx4){0.f, 0.f, 0.f, 0.f};
      accu[i][j] = (floatx4){0.f, 0.f, 0.f, 0.f};
    }
  for (int k0 = 0; k0 < D_DIM; k0 += 32) {
#pragma unroll
    for (int j = 0; j < 2; j++) {
      DMA16(sA[j] + k0, As + dof[j]);
      DMA16(sBg[j] + k0, Bg + dof[j]);
      DMA16(sBu[j] + k0, Bu + dof[j]);
    }
    __syncthreads();
    short8 aF[4], gF[4], uF[4];
#pragma unroll
    for (int mt = 0; mt < 4; mt++) aF[mt] = *(short8*)&As[quad * 1024 + (wm + mt * 16 + l15) * 8];
#pragma unroll
    for (int nt = 0; nt < 4; nt++) {
      gF[nt] = *(short8*)&Bg[quad * 1024 + (wn + nt * 16 + l15) * 8];
      uF[nt] = *(short8*)&Bu[quad * 1024 + (wn + nt * 16 + l15) * 8];
    }
#pragma unroll
    for (int mt = 0; mt < 4; mt++)
#pragma unroll
      for (int nt = 0; nt < 4; nt++) {
        accg[mt][nt] = mfma16(aF[mt], gF[nt], accg[mt][nt]);
        accu[mt][nt] = mfma16(aF[mt], uF[nt], accu[mt][nt]);
      }
    __syncthreads();
  }
  int aoff = offsets[e];
#pragma unroll
  for (int mt = 0; mt < 4; mt++) {
    int mrow = wm + mt * 16 + quad * 4;
#pragma unroll
    for (int nt = 0; nt < 4; nt++) {
      int col = n0 + wn + nt * 16 + l15;
      if (col < FF) {
#pragma unroll
        for (int r = 0; r < 4; r++) {
          int ml = mrow + r;
          if (m0 + ml < cnt) {
            float g = accg[mt][nt][r];
            float u = accu[mt][nt][r];
            float sil = g / (1.f + __expf(-g));
            act[(size_t)(aoff + m0 + ml) * FF + col] = f2bf(sil * u * wrow[ml]);
          }
        }
      }
    }
  }
}

// ---------------- MoE down bf16 MFMA GEMM (DMA-staged), scatter-add ----------------
__global__ __launch_bounds__(256) void k_moe_down(const ushort* __restrict__ act,
                                                  const ushort* __restrict__ wdT,
                                                  const int* __restrict__ ids,
                                                  const int* __restrict__ counts,
                                                  const int* __restrict__ offsets,
                                                  float* __restrict__ moe_acc) {
  int e = blockIdx.z;
  int cnt = counts[e];
  int m0 = blockIdx.y * 128;
  if (m0 >= cnt) return;
  int n0 = blockIdx.x * 128;
  __shared__ __align__(16) ushort As[4096], Bs[4096];
  __shared__ int toks[128];
  int tid = threadIdx.x;
  if (tid < 128) {
    int mm = m0 + tid;
    toks[tid] = (mm < cnt) ? ids[e * NTOK + mm] : 0;
  }
  __syncthreads();
  int wave = tid >> 6, lane = tid & 63, quad = lane >> 4, l15 = lane & 15;
  int wm = (wave >> 1) * 64, wn = (wave & 1) * 64;
  int aoff = offsets[e];
  const ushort* Wd = wdT + (size_t)e * D_DIM * FF;
  const ushort *sA[2], *sB[2];
  int dof[2];
#pragma unroll
  for (int j = 0; j < 2; j++) {
    int u = (wave * 2 + j) * 64 + lane;
    int chunk = u >> 7, row = u & 127;
    sA[j] = act + (size_t)(aoff + m0 + row) * FF + chunk * 8;
    sB[j] = Wd + (size_t)(n0 + row) * FF + chunk * 8;
    dof[j] = (wave * 2 + j) * 512;
  }
  floatx4 acc[4][4];
#pragma unroll
  for (int i = 0; i < 4; i++)
#pragma unroll
    for (int j = 0; j < 4; j++) acc[i][j] = (floatx4){0.f, 0.f, 0.f, 0.f};
  for (int k0 = 0; k0 < FF; k0 += 32) {
#pragma unroll
    for (int j = 0; j < 2; j++) {
      DMA16(sA[j] + k0, As + dof[j]);
      DMA16(sB[j] + k0, Bs + dof[j]);
    }
    __syncthreads();
    short8 aF[4], bF[4];
#pragma unroll
    for (int mt = 0; mt < 4; mt++) aF[mt] = *(short8*)&As[quad * 1024 + (wm + mt * 16 + l15) * 8];
#pragma unroll
    for (int nt = 0; nt < 4; nt++) bF[nt] = *(short8*)&Bs[quad * 1024 + (wn + nt * 16 + l15) * 8];
#pragma unroll
    for (int mt = 0; mt < 4; mt++)
#pragma unroll
      for (int nt = 0; nt < 4; nt++) acc[mt][nt] = mfma16(aF[mt], bF[nt], acc[mt][nt]);
    __syncthreads();
  }
#pragma unroll
  for (int mt = 0; mt < 4; mt++) {
    int mrow = wm + mt * 16 + quad * 4;
#pragma unroll
    for (int nt = 0; nt < 4; nt++) {
      int col = n0 + wn + nt * 16 + l15;
#pragma unroll
      for (int r = 0; r < 4; r++) {
        int ml = mrow + r;
        if (m0 + ml < cnt)
          atomicAdd(&moe_acc[(size_t)toks[ml] * D_DIM + col], acc[mt][nt][r]);
      }
    }
  }
}

__global__ __launch_bounds__(256) void k_add(const float* __restrict__ a,
                                             const float* __restrict__ b,
                                             float* __restrict__ o) {
  int i = blockIdx.x * 256 + threadIdx.x;
  float4 va = ((const float4*)a)[i];
  float4 vb = ((const float4*)b)[i];
  float4 vo;
  vo.x = va.x + vb.x; vo.y = va.y + vb.y; vo.z = va.z + vb.z; vo.w = va.w + vb.w;
  ((float4*)o)[i] = vo;
}

__global__ void k_aux(const int* __restrict__ counts, const float* __restrict__ load_sum,
                      float* __restrict__ out_aux) {
  if (threadIdx.x == 0 && blockIdx.x == 0) {
    float s = 0.f;
    for (int e = 0; e < NE; e++)
      s += ((float)counts[e] / (float)NSLOT) * (load_sum[e] / (float)NTOK);
    *out_aux = 0.01f * (float)NE * s;
  }
}

extern "C" void kernel_launch(void* const* d_in, const int* in_sizes, int n_in,
                              void* d_out, int out_size, void* d_ws, size_t ws_size,
                              hipStream_t stream) {
  const float* x = (const float*)d_in[0];
  const float* g1 = (const float*)d_in[1];
  const float* g2 = (const float*)d_in[2];
  const float* wq = (const float*)d_in[3];
  const float* wk = (const float*)d_in[4];
  const float* wv = (const float*)d_in[5];
  const float* wo = (const float*)d_in[6];
  const float* gate_w = (const float*)d_in[7];
  const float* we_gate = (const float*)d_in[8];
  const float* we_up = (const float*)d_in[9];
  const float* we_down = (const float*)d_in[10];
  float* out = (float*)d_out;

  char* w = (char*)d_ws;
  size_t o = 0;
  auto alloc = [&](size_t bytes) -> char* {
    char* p = w + o;
    o = (o + bytes + 255) & ~(size_t)255;
    return p;
  };
  ushort* h1h = (ushort*)alloc((size_t)NTOK * D_DIM * 2);
  ushort* h1l = (ushort*)alloc((size_t)NTOK * D_DIM * 2);
  float* qkvf = (float*)alloc((size_t)NTOK * 1536 * 4);
  float* qbh = (float*)alloc((size_t)HQn * T_LEN * 64 * 4);
  float* kbh = (float*)alloc((size_t)HKVn * T_LEN * 64 * 4);
  float* vbt = (float*)alloc((size_t)HKVn * 64 * T_LEN * 4);
  ushort* obh = (ushort*)alloc((size_t)NTOK * D_DIM * 2);
  ushort* obl = (ushort*)alloc((size_t)NTOK * D_DIM * 2);
  float* x1 = (float*)alloc((size_t)NTOK * D_DIM * 4);
  float* moe_acc = (float*)alloc((size_t)NTOK * D_DIM * 4);
  ushort* act = (ushort*)alloc((size_t)(NSLOT + 128) * FF * 2);
  ushort* qkvwTh = (ushort*)alloc((size_t)1536 * 1024 * 2);
  ushort* qkvwTl = (ushort*)alloc((size_t)1536 * 1024 * 2);
  ushort* woTh = (ushort*)alloc((size_t)1024 * 1024 * 2);
  ushort* woTl = (ushort*)alloc((size_t)1024 * 1024 * 2);
  ushort* h2h = (ushort*)alloc((size_t)NTOK * D_DIM * 2);
  ushort* h2l = (ushort*)alloc((size_t)NTOK * D_DIM * 2);
  ushort* wgT = (ushort*)alloc((size_t)NE * FF * D_DIM * 2);
  ushort* wuT = (ushort*)alloc((size_t)NE * FF * D_DIM * 2);
  ushort* wdT = (ushort*)alloc((size_t)NE * D_DIM * FF * 2);
  int* counts = (int*)alloc(NE * 4);
  int* offsets = (int*)alloc(NE * 4);
  float* load_sum = (float*)alloc(NE * 4);
  int* ids = (int*)alloc((size_t)NE * NTOK * 4);
  float* wts = (float*)alloc((size_t)NE * NTOK * 4);

  hipMemsetAsync(moe_acc, 0, (size_t)NTOK * D_DIM * 4, stream);
  hipMemsetAsync(counts, 0, 768, stream);  // counts+offsets+load_sum slots

  // weight transposes (hi/lo split for fp32-accurate attention path, bf16 for experts)
  k_cvtT2<<<dim3(32, 32), 256, 0, stream>>>(wq, qkvwTh, qkvwTl, 1024, 1024);
  k_cvtT2<<<dim3(8, 32), 256, 0, stream>>>(wk, qkvwTh + (size_t)1024 * 1024,
                                           qkvwTl + (size_t)1024 * 1024, 1024, 256);
  k_cvtT2<<<dim3(8, 32), 256, 0, stream>>>(wv, qkvwTh + (size_t)1280 * 1024,
                                           qkvwTl + (size_t)1280 * 1024, 1024, 256);
  k_cvtT2<<<dim3(32, 32), 256, 0, stream>>>(wo, woTh, woTl, 1024, 1024);
  k_cvtT<<<dim3(86, 32, 8), 256, 0, stream>>>(we_gate, wgT, 1024, 2752);
  k_cvtT<<<dim3(86, 32, 8), 256, 0, stream>>>(we_up, wuT, 1024, 2752);
  k_cvtT<<<dim3(32, 86, 8), 256, 0, stream>>>(we_down, wdT, 2752, 1024);

  // attention path (fp32-accurate via split-bf16 MFMA)
  k_rmsnorm2<<<NTOK, 256, 0, stream>>>(x, g1, h1h, h1l);
  k_sgemm<<<dim3(12, 16), 256, 0, stream>>>(h1h, h1l, qkvwTh, qkvwTl, qkvf, nullptr,
                                            1536, 1024);
  k_rope_cvt<<<T_LEN, 256, 0, stream>>>(qkvf, qbh, kbh);
  k_vT<<<dim3(64, 8), 256, 0, stream>>>(qkvf, vbt);
  k_attn<<<dim3(32, 16), 256, 0, stream>>>(qbh, kbh, vbt, obh, obl);
  k_sgemm<<<dim3(8, 16), 256, 0, stream>>>(obh, obl, woTh, woTl, x1, x, 1024, 1024);

  // moe
  k_rmsnorm2<<<NTOK, 256, 0, stream>>>(x1, g2, h2h, h2l);
  k_gate<<<NTOK / GATE_TPB, 256, 0, stream>>>(x1, g2, gate_w, counts, ids, wts, load_sum);
  k_offsets<<<1, 1, 0, stream>>>(counts, offsets);
  k_moe_gateup<<<dim3(22, 16, 8), 256, 0, stream>>>(h2h, wgT, wuT, ids, wts, counts,
                                                    offsets, act);
  k_moe_down<<<dim3(8, 16, 8), 256, 0, stream>>>(act, wdT, ids, counts, offsets, moe_acc);
  k_add<<<(NTOK * D_DIM) / (256 * 4), 256, 0, stream>>>(x1, moe_acc, out);
  k_aux<<<1, 1, 0, stream>>>(counts, load_sum, out + (size_t)NTOK * D_DIM);
}